// Round 10
// baseline (409.146 us; speedup 1.0000x reference)
//
#include <hip/hip_runtime.h>
#include <hip/hip_bf16.h>
#include <cfloat>
#include <math.h>

#define BB 64
#define NN 1024
#define KNN 20
#define MM 256
#define CC 64
#define HH 512
#define NCLS 40
#define EPSF 1e-5f
#define CNT1 (BB*NN*KNN)

// FPS phase boundaries: phase1 rounds [1,FPS_R1), phase2 [FPS_R1,FPS_R2),
// phase3 [FPS_R2,MM). Tuned to hide each slice under its host dispatch.
#define FPS_R1 131
#define FPS_R2 176

// workspace offsets (in 4-byte elements)
#define IDX_OFF    0
#define MAXH2_OFF  (IDX_OFF + BB*NN*KNN)      // int idx then floats
#define FIDX_OFF   (MAXH2_OFF + BB*NN*CC)
#define Y_OFF      (FIDX_OFF + BB*MM)
#define ACC_OFF    (Y_OFF + BB*HH)            // 256 floats zeroed: sum1[64],sumsq1[64],sum2[64],sumsq2[64]
#define W2T_OFF    (ACC_OFF + 256)            // w2' bf16 B-frags (2048 ushorts) + b2f
#define B2F_OFF    (W2T_OFF + CC*CC)
#define S2_OFF     (B2F_OFF + CC)
#define T2_OFF     (S2_OFF + CC)
#define S3_OFF     (T2_OFF + CC)
#define T3_OFF     (S3_OFF + HH)
#define FPSD_OFF   (T3_OFF + HH)              // BB*NN floats: FPS dist state
#define FPSC_OFF   (FPSD_OFF + BB*NN)         // BB ints: FPS cur state

typedef __attribute__((ext_vector_type(8)))  short short8;
typedef __attribute__((ext_vector_type(16))) float f32x16;

static __device__ __forceinline__ unsigned short f2bf(float f) {
  unsigned u = __float_as_uint(f);
  unsigned r = (u + 0x7fffu + ((u >> 16) & 1u)) >> 16;   // RNE
  return (unsigned short)r;
}

// popcount(mask & ((1<<lane)-1)) via native mbcnt pair
static __device__ __forceinline__ int mbcnt64(unsigned long long m) {
  return (int)__builtin_amdgcn_mbcnt_hi((unsigned)(m >> 32),
           __builtin_amdgcn_mbcnt_lo((unsigned)m, 0));
}

// ---------------- generic kNN emission (fast or slow path), wave-uniform ----------------
static __device__ __forceinline__ void knn_emit_generic(const unsigned* u, unsigned phi,
                                                        int cntHi, int* op, int lane) {
  unsigned tstar = (phi << 16) | 0xFFFFu;
  unsigned bbase = phi << 16;
  if (cntHi == KNN) {
    int base = 0;
#pragma unroll
    for (int q = 0; q < 16; ++q) {
      bool pred = (u[q] <= tstar);
      unsigned long long mask = __ballot((int)pred);
      if (pred) op[base + mbcnt64(mask)] = q*64 + lane;
      base += (int)__popcll(mask);
    }
  } else {
    // refine low 16 bits -> exact 20th value xstar
    unsigned lo2 = bbase, hi2 = tstar;
    while (lo2 < hi2) {
      unsigned mid = lo2 + ((hi2 - lo2) >> 1);
      int cnt = 0;
#pragma unroll
      for (int q = 0; q < 16; ++q)
        cnt += (int)__popcll(__ballot(u[q] <= mid));
      if (cnt >= KNN) hi2 = mid; else lo2 = mid + 1;
    }
    unsigned xstar = lo2;
    int base = 0;
#pragma unroll
    for (int q = 0; q < 16; ++q) {
      bool pred = (u[q] < xstar);
      unsigned long long mask = __ballot((int)pred);
      if (pred) op[base + mbcnt64(mask)] = q*64 + lane;
      base += (int)__popcll(mask);
    }
    for (int q = 0; q < 16 && base < KNN; ++q) {  // ties, ascending index
      bool pred = (u[q] == xstar);
      unsigned long long mask = __ballot((int)pred);
      if (pred) {
        int pos_ = base + mbcnt64(mask);
        if (pos_ < KNN) op[pos_] = q*64 + lane;
      }
      base += (int)__popcll(mask);
    }
  }
}

// ---------------- FPS phase (single wave; caller: threadIdx.x < 64) ----------------
static __device__ __forceinline__ void fps_phase(
    const float* sx, const float* sy, const float* sz,   // LDS, NN each
    float* fpsd, int* fpsc, int* fidxg, int b, int mStart, int mEnd) {
  int lane = threadIdx.x;
  float lx[16], ly[16], lz[16], dist[16];
#pragma unroll
  for (int q = 0; q < 16; ++q) {
    int j = q*64 + lane;
    lx[q] = sx[j]; ly[q] = sy[j]; lz[q] = sz[j];
  }
  int cur;
  if (mStart <= 1) {
#pragma unroll
    for (int q = 0; q < 16; ++q) dist[q] = 1e38f;
    if (lane == 0) fidxg[b*MM] = 0;
    cur = 0;
  } else {
#pragma unroll
    for (int q = 0; q < 16; ++q) dist[q] = fpsd[b*NN + q*64 + lane];
    cur = fpsc[b];
  }
  for (int m = mStart; m < mEnd; ++m) {
    float cpx = sx[cur], cpy = sy[cur], cpz = sz[cur];   // uniform LDS broadcast
#pragma unroll
    for (int q = 0; q < 16; ++q) {
      float dx = __fsub_rn(lx[q], cpx);
      float dy = __fsub_rn(ly[q], cpy);
      float dz = __fsub_rn(lz[q], cpz);
      float dd = __fadd_rn(__fadd_rn(__fmul_rn(dx,dx), __fmul_rn(dy,dy)), __fmul_rn(dz,dz));
      dist[q] = fminf(dist[q], dd);
    }
    float t8[8];
#pragma unroll
    for (int q = 0; q < 8; ++q) t8[q] = fmaxf(dist[q], dist[q + 8]);
#pragma unroll
    for (int q = 0; q < 4; ++q) t8[q] = fmaxf(t8[q], t8[q + 4]);
    float r = fmaxf(fmaxf(t8[0], t8[1]), fmaxf(t8[2], t8[3]));
#define FPS_VMAX_STEP(C) { \
    int tt = __builtin_amdgcn_update_dpp(__float_as_int(r), __float_as_int(r), (C), 0xf, 0xf, false); \
    r = fmaxf(r, __int_as_float(tt)); }
    FPS_VMAX_STEP(0x111)   // row_shr:1
    FPS_VMAX_STEP(0x112)   // row_shr:2
    FPS_VMAX_STEP(0x114)   // row_shr:4
    FPS_VMAX_STEP(0x118)   // row_shr:8
    FPS_VMAX_STEP(0x142)   // row_bcast:15
    FPS_VMAX_STEP(0x143)   // row_bcast:31
#undef FPS_VMAX_STEP
    float wmax = __int_as_float(__builtin_amdgcn_readlane(__float_as_int(r), 63));
    unsigned ci = 0xFFFFFFFFu;
#pragma unroll
    for (int q = 15; q >= 0; --q)
      if (dist[q] == wmax) ci = (unsigned)(q*64 + lane);
#define FPS_IMIN_STEP(C) { \
    unsigned tt = (unsigned)__builtin_amdgcn_update_dpp((int)ci, (int)ci, (C), 0xf, 0xf, false); \
    ci = (tt < ci) ? tt : ci; }
    FPS_IMIN_STEP(0x111)
    FPS_IMIN_STEP(0x112)
    FPS_IMIN_STEP(0x114)
    FPS_IMIN_STEP(0x118)
    FPS_IMIN_STEP(0x142)
    FPS_IMIN_STEP(0x143)
#undef FPS_IMIN_STEP
    cur = (int)(unsigned)__builtin_amdgcn_readlane((int)ci, 63);
    if (lane == 0) fidxg[b*MM + m] = cur;
  }
  if (mEnd < MM) {   // checkpoint
#pragma unroll
    for (int q = 0; q < 16; ++q) fpsd[b*NN + q*64 + lane] = dist[q];
    if (lane == 0) fpsc[b] = cur;
  }
}

// ---------------- fused FPS(phase1) + kNN ----------------
// blocks [0, BB): FPS rounds [1, FPS_R1).
// blocks [BB, BB + BB*32): kNN, one wave per 8 queries, processed in PAIRS:
// shared pw read feeds both distance sets; DPP bound chains, binary-search
// steps and fast-path emission are interleaved across the pair so the two
// independent v_cmp->s_bcnt serial chains fill each other's stall slots.
// Per-query arithmetic identical to R6-R9 -> bit-identical neighbor sets.
__global__ __launch_bounds__(256) void knn_fps_kernel(const float* __restrict__ pos,
                                                      int* __restrict__ idxg,
                                                      int* __restrict__ fidxg,
                                                      float* __restrict__ fpsd,
                                                      int* __restrict__ fpsc) {
  __shared__ float4 pj[NN];
  if (blockIdx.x >= BB) {
    // ---------------- kNN branch ----------------
    int blk = blockIdx.x - BB;
    int b  = blk >> 5;   // cloud
    int nb = blk & 31;   // 32-point segment of the cloud
    const float* pb = pos + (size_t)b * NN * 3;
    for (int i = threadIdx.x; i < NN; i += 256) {
      float x = pb[i*3+0], y = pb[i*3+1], z = pb[i*3+2];
      pj[i] = make_float4(x, y, z, (x*x + y*y) + z*z);
    }
    __syncthreads();
    int lane = threadIdx.x & 63;
    int wv   = threadIdx.x >> 6;

    for (int t = 0; t < 4; ++t) {
      int iA = nb*32 + wv*8 + 2*t;     // query pair (wave-uniform)
      int iB = iA + 1;
      float4 piA = pj[iA];
      float4 piB = pj[iB];
      unsigned uA[16], uB[16];
#pragma unroll
      for (int q = 0; q < 16; ++q) {
        int j = q*64 + lane;
        float4 pw = pj[j];             // shared between the pair
        float dA = piA.w + pw.w - 2.0f*(piA.x*pw.x + piA.y*pw.y + piA.z*pw.z);
        float dB = piB.w + pw.w - 2.0f*(piB.x*pw.x + piB.y*pw.y + piB.z*pw.z);
        unsigned ba = __float_as_uint(dA);
        ba = (ba & 0x80000000u) ? ~ba : (ba | 0x80000000u);
        if (j == iA) ba = 0xFFFFFFFFu;
        uA[q] = ba;
        unsigned bb2 = __float_as_uint(dB);
        bb2 = (bb2 & 0x80000000u) ? ~bb2 : (bb2 | 0x80000000u);
        if (j == iB) bb2 = 0xFFFFFFFFu;
        uB[q] = bb2;
      }
      // per-lane mins, then interleaved DPP wave-min / wave-max-of-lane-mins
      unsigned lminA = uA[0], lminB = uB[0];
#pragma unroll
      for (int q = 1; q < 16; ++q) {
        lminA = (uA[q] < lminA) ? uA[q] : lminA;
        lminB = (uB[q] < lminB) ? uB[q] : lminB;
      }
      unsigned rminA = lminA, rmaxA = lminA, rminB = lminB, rmaxB = lminB;
#define KNN_DPP_STEP(C) { \
      unsigned t1 = (unsigned)__builtin_amdgcn_update_dpp((int)rminA, (int)rminA, (C), 0xf, 0xf, false); \
      unsigned t2 = (unsigned)__builtin_amdgcn_update_dpp((int)rmaxA, (int)rmaxA, (C), 0xf, 0xf, false); \
      unsigned t3 = (unsigned)__builtin_amdgcn_update_dpp((int)rminB, (int)rminB, (C), 0xf, 0xf, false); \
      unsigned t4 = (unsigned)__builtin_amdgcn_update_dpp((int)rmaxB, (int)rmaxB, (C), 0xf, 0xf, false); \
      rminA = (t1 < rminA) ? t1 : rminA; rmaxA = (t2 > rmaxA) ? t2 : rmaxA; \
      rminB = (t3 < rminB) ? t3 : rminB; rmaxB = (t4 > rmaxB) ? t4 : rmaxB; }
      KNN_DPP_STEP(0x111)   // row_shr:1
      KNN_DPP_STEP(0x112)   // row_shr:2
      KNN_DPP_STEP(0x114)   // row_shr:4
      KNN_DPP_STEP(0x118)   // row_shr:8
      KNN_DPP_STEP(0x142)   // row_bcast:15
      KNN_DPP_STEP(0x143)   // row_bcast:31
#undef KNN_DPP_STEP
      unsigned ploA = ((unsigned)__builtin_amdgcn_readlane((int)rminA, 63)) >> 16;
      unsigned phiA = ((unsigned)__builtin_amdgcn_readlane((int)rmaxA, 63)) >> 16;
      unsigned ploB = ((unsigned)__builtin_amdgcn_readlane((int)rminB, 63)) >> 16;
      unsigned phiB = ((unsigned)__builtin_amdgcn_readlane((int)rmaxB, 63)) >> 16;
      // fused binary search: both queries step per iteration
      int cntHiA = -1, cntHiB = -1;
      while (ploA < phiA || ploB < phiB) {   // wave-uniform
        unsigned pmA = (ploA + phiA) >> 1, pmB = (ploB + phiB) >> 1;
        unsigned tA = (pmA << 16) | 0xFFFFu, tB = (pmB << 16) | 0xFFFFu;
        int cA = 0, cB = 0;
#pragma unroll
        for (int q = 0; q < 16; ++q) {
          cA += (int)__popcll(__ballot(uA[q] <= tA));
          cB += (int)__popcll(__ballot(uB[q] <= tB));
        }
        if (ploA < phiA) { if (cA >= KNN) { phiA = pmA; cntHiA = cA; } else ploA = pmA + 1; }
        if (ploB < phiB) { if (cB >= KNN) { phiB = pmB; cntHiB = cB; } else ploB = pmB + 1; }
      }
      if (cntHiA < 0 || cntHiB < 0) {        // fused recount at final phi
        unsigned tsA = (phiA << 16) | 0xFFFFu, tsB = (phiB << 16) | 0xFFFFu;
        int cA = 0, cB = 0;
#pragma unroll
        for (int q = 0; q < 16; ++q) {
          cA += (int)__popcll(__ballot(uA[q] <= tsA));
          cB += (int)__popcll(__ballot(uB[q] <= tsB));
        }
        if (cntHiA < 0) cntHiA = cA;
        if (cntHiB < 0) cntHiB = cB;
      }
      int* opA = idxg + (size_t)(b*NN + iA) * KNN;
      int* opB = idxg + (size_t)(b*NN + iB) * KNN;
      if (cntHiA == KNN && cntHiB == KNN) {
        // interleaved fast-path emission (dual independent base chains)
        unsigned tsA = (phiA << 16) | 0xFFFFu, tsB = (phiB << 16) | 0xFFFFu;
        int baseA = 0, baseB = 0;
#pragma unroll
        for (int q = 0; q < 16; ++q) {
          bool pA = (uA[q] <= tsA);
          unsigned long long mA = __ballot((int)pA);
          bool pB = (uB[q] <= tsB);
          unsigned long long mB = __ballot((int)pB);
          if (pA) opA[baseA + mbcnt64(mA)] = q*64 + lane;
          if (pB) opB[baseB + mbcnt64(mB)] = q*64 + lane;
          baseA += (int)__popcll(mA);
          baseB += (int)__popcll(mB);
        }
      } else {
        knn_emit_generic(uA, phiA, cntHiA, opA, lane);
        knn_emit_generic(uB, phiB, cntHiB, opB, lane);
      }
    }
  } else {
    // ---------------- FPS phase 1 ----------------
    int b = blockIdx.x;
    float* base = (float*)pj;            // reuse 16 KB as 3 x NN floats
    float* sx = base; float* sy = base + NN; float* sz = base + 2*NN;
    const float* pb = pos + (size_t)b * NN * 3;
    for (int i = threadIdx.x; i < NN; i += 256) {
      sx[i] = pb[i*3+0]; sy[i] = pb[i*3+1]; sz[i] = pb[i*3+2];
    }
    __syncthreads();
    if (threadIdx.x >= 64) return;
    fps_phase(sx, sy, sz, fpsd, fpsc, fidxg, b, 1, FPS_R1);
  }
}

// ---------------- stats of h1 + FPS phase 2 ----------------
__global__ __launch_bounds__(256) void stats1_kernel(const float* __restrict__ pos,
    const int* __restrict__ idxg, const float* __restrict__ w1,
    const float* __restrict__ b1, float* __restrict__ acc,
    int* __restrict__ fidxg, float* __restrict__ fpsd, int* __restrict__ fpsc) {
  __shared__ float px[NN], py[NN], pz[NN];
  __shared__ float relx[4][KNN], rely[4][KNN], relz[4][KNN];
  __shared__ float red[4][CC];
  if (blockIdx.x < BB) {
    // ---------------- FPS phase 2 ----------------
    int b = blockIdx.x;
    const float* pb = pos + (size_t)b*NN*3;
    for (int i = threadIdx.x; i < NN; i += 256) {
      px[i] = pb[i*3+0]; py[i] = pb[i*3+1]; pz[i] = pb[i*3+2];
    }
    __syncthreads();
    if (threadIdx.x >= 64) return;
    fps_phase(px, py, pz, fpsd, fpsc, fidxg, b, FPS_R1, FPS_R2);
    return;
  }
  int blk = blockIdx.x - BB;
  int b = blk >> 4;
  int nb = blk & 15;
  const float* pb = pos + (size_t)b*NN*3;
  for (int i = threadIdx.x; i < NN; i += 256) {
    px[i] = pb[i*3+0]; py[i] = pb[i*3+1]; pz[i] = pb[i*3+2];
  }
  int c = threadIdx.x & 63, w = threadIdx.x >> 6;
  float w1x = w1[c*3+0], w1y = w1[c*3+1], w1z = w1[c*3+2], b1c = b1[c];
  float s = 0.f, ss = 0.f;
  __syncthreads();
  for (int it = 0; it < 16; ++it) {
    int n0 = nb*64 + it*4;
    if (threadIdx.x < 80) {
      int wv = threadIdx.x / KNN, k = threadIdx.x % KNN;
      int n = n0 + wv;
      int j = idxg[(size_t)(b*NN + n)*KNN + k];
      relx[wv][k] = px[j] - px[n];
      rely[wv][k] = py[j] - py[n];
      relz[wv][k] = pz[j] - pz[n];
    }
    __syncthreads();
#pragma unroll
    for (int k = 0; k < KNN; ++k) {
      float h = fmaxf(relx[w][k]*w1x + rely[w][k]*w1y + relz[w][k]*w1z + b1c, 0.f);
      s += h; ss += h*h;
    }
    __syncthreads();
  }
  red[w][c] = s; __syncthreads();
  if (w == 0) atomicAdd(&acc[c], red[0][c]+red[1][c]+red[2][c]+red[3][c]);
  __syncthreads();
  red[w][c] = ss; __syncthreads();
  if (w == 0) atomicAdd(&acc[64+c], red[0][c]+red[1][c]+red[2][c]+red[3][c]);
}

// ---------------- fold BN1 into w2 (bf16 B-fragment layout) ----------------
__global__ void fold1_kernel(const float* __restrict__ acc, const float* __restrict__ g1,
    const float* __restrict__ be1, const float* __restrict__ w2, const float* __restrict__ b2,
    unsigned short* __restrict__ w2bf, float* __restrict__ b2f) {
  __shared__ float s1[CC], t1[CC];
  int tid = threadIdx.x;  // 512 threads
  if (tid < CC) {
    float cnt = (float)CNT1;
    float m = acc[tid] / cnt;
    float v = acc[64+tid] / cnt - m*m;
    float sc = g1[tid] * rsqrtf(v + EPSF);
    s1[tid] = sc; t1[tid] = be1[tid] - m*sc;
  }
  __syncthreads();
  int frag = tid >> 6;        // 0..7  (nt = frag>>2, ks = frag&3)
  int lane = tid & 63;
  int nt = frag >> 2, ks = frag & 3;
  int cout = nt*32 + (lane & 31);
  int cin0 = ks*16 + (lane >> 5)*8;
  for (int j = 0; j < 8; ++j) {
    int cin = cin0 + j;
    w2bf[((size_t)frag*64 + lane)*8 + j] = f2bf(w2[cout*CC + cin] * s1[cin]);
  }
  if (tid < CC) {
    float accb = b2[tid];
    for (int ci = 0; ci < CC; ++ci) accb += t1[ci]*w2[tid*CC + ci];
    b2f[tid] = accb;
  }
}

// ---------------- conv2 via MFMA + FPS phase 3 ----------------
__global__ __launch_bounds__(256, 4) void conv2_kernel(const float* __restrict__ pos,
    const int* __restrict__ idxg, const float* __restrict__ w1, const float* __restrict__ b1,
    const unsigned short* __restrict__ w2bf, const float* __restrict__ b2fg,
    float* __restrict__ maxh2, float* __restrict__ acc2,
    int* __restrict__ fidxg, float* __restrict__ fpsd, int* __restrict__ fpsc) {
  __shared__ float px[NN], py[NN], pz[NN];
  __shared__ float4 relw[4][KNN];
  __shared__ __align__(16) unsigned short h1s[4][2112];  // 8 groups * 264 ushorts
  __shared__ float redbuf[4][2*CC];
  if (blockIdx.x < BB) {
    // ---------------- FPS phase 3 ----------------
    int b = blockIdx.x;
    const float* pb = pos + (size_t)b*NN*3;
    for (int i = threadIdx.x; i < NN; i += 256) {
      px[i] = pb[i*3+0]; py[i] = pb[i*3+1]; pz[i] = pb[i*3+2];
    }
    __syncthreads();
    if (threadIdx.x >= 64) return;
    fps_phase(px, py, pz, fpsd, fpsc, fidxg, b, FPS_R2, MM);
    return;
  }
  int blk = blockIdx.x - BB;
  int b = blk >> 4;
  int nb = blk & 15;
  const float* pb = pos + (size_t)b*NN*3;
  for (int i = threadIdx.x; i < NN; i += 256) {
    px[i] = pb[i*3+0]; py[i] = pb[i*3+1]; pz[i] = pb[i*3+2];
  }
  int lane = threadIdx.x & 63, w = threadIdx.x >> 6;
  int half = lane >> 5, l31 = lane & 31;
  short8 Bf[2][4];
#pragma unroll
  for (int nt = 0; nt < 2; ++nt)
#pragma unroll
    for (int ks = 0; ks < 4; ++ks)
      Bf[nt][ks] = *(const short8*)&w2bf[((size_t)(nt*4+ks)*64 + lane)*8];
  float b2o0 = b2fg[l31], b2o1 = b2fg[32 + l31];
  float w1x = w1[lane*3+0], w1y = w1[lane*3+1], w1z = w1[lane*3+2], b1c = b1[lane];
  unsigned short* hw = h1s[w];
  {
    short8 zz = {0,0,0,0,0,0,0,0};
    for (int z = lane; z < 96; z += 64) {
      int g = z / 12, r = 20 + z % 12;
      *(short8*)&hw[g*264 + r*8] = zz;
    }
  }
  float sA = 0.f, ssA = 0.f, sB = 0.f, ssB = 0.f;
  __syncthreads();
  for (int t = 0; t < 16; ++t) {
    int n = nb*64 + w*16 + t;
    if (lane < KNN) {
      int j = idxg[(size_t)(b*NN + n)*KNN + lane];
      relw[w][lane] = make_float4(px[j]-px[n], py[j]-py[n], pz[j]-pz[n], 0.f);
    }
    int gbase = (lane >> 3)*264 + (lane & 7);
#pragma unroll
    for (int k = 0; k < KNN; ++k) {
      float4 r4 = relw[w][k];   // wave-uniform broadcast read
      float h = fmaxf(fmaf(r4.x, w1x, fmaf(r4.y, w1y, fmaf(r4.z, w1z, b1c))), 0.f);
      hw[gbase + k*8] = f2bf(h);
    }
    f32x16 acc0 = {}; f32x16 acc1 = {};
#pragma unroll
    for (int ks = 0; ks < 4; ++ks) {
      short8 A = *(const short8*)&hw[(ks*2 + half)*264 + l31*8];
      acc0 = __builtin_amdgcn_mfma_f32_32x32x16_bf16(A, Bf[0][ks], acc0, 0, 0, 0);
      acc1 = __builtin_amdgcn_mfma_f32_32x32x16_bf16(A, Bf[1][ks], acc1, 0, 0, 0);
    }
    float mx0 = 0.f, mx1 = 0.f;
#pragma unroll
    for (int reg = 0; reg < 8; ++reg) {
      float v0 = fmaxf(acc0[reg] + b2o0, 0.f);
      float v1 = fmaxf(acc1[reg] + b2o1, 0.f);
      sA += v0; ssA += v0*v0; sB += v1; ssB += v1*v1;
      mx0 = fmaxf(mx0, v0); mx1 = fmaxf(mx1, v1);
    }
    if (half == 0) {
#pragma unroll
      for (int reg = 8; reg < 12; ++reg) {
        float v0 = fmaxf(acc0[reg] + b2o0, 0.f);
        float v1 = fmaxf(acc1[reg] + b2o1, 0.f);
        sA += v0; ssA += v0*v0; sB += v1; ssB += v1*v1;
        mx0 = fmaxf(mx0, v0); mx1 = fmaxf(mx1, v1);
      }
    }
    mx0 = fmaxf(mx0, __shfl_xor(mx0, 32, 64));
    mx1 = fmaxf(mx1, __shfl_xor(mx1, 32, 64));
    if (half == 0) {
      float* mp = maxh2 + (size_t)(b*NN + n)*CC;
      mp[l31] = mx0; mp[32 + l31] = mx1;
    }
  }
  sA += __shfl_xor(sA, 32, 64); ssA += __shfl_xor(ssA, 32, 64);
  sB += __shfl_xor(sB, 32, 64); ssB += __shfl_xor(ssB, 32, 64);
  if (half == 0) { redbuf[w][l31] = sA; redbuf[w][32 + l31] = sB; }
  __syncthreads();
  if (w == 0) atomicAdd(&acc2[lane], redbuf[0][lane]+redbuf[1][lane]+redbuf[2][lane]+redbuf[3][lane]);
  __syncthreads();
  if (half == 0) { redbuf[w][l31] = ssA; redbuf[w][32 + l31] = ssB; }
  __syncthreads();
  if (w == 0) atomicAdd(&acc2[64+lane], redbuf[0][lane]+redbuf[1][lane]+redbuf[2][lane]+redbuf[3][lane]);
}

// ---------------- finalize BN2 affine ----------------
__global__ void fold2_kernel(const float* __restrict__ acc2, const float* __restrict__ g2,
    const float* __restrict__ be2, float* __restrict__ s2, float* __restrict__ t2) {
  int c = threadIdx.x;
  float cnt = (float)CNT1;
  float m = acc2[c]/cnt;
  float v = acc2[64+c]/cnt - m*m;
  float sc = g2[c]*rsqrtf(v+EPSF);
  s2[c] = sc;
  t2[c] = be2[c] - m*sc;
}

// ---------------- head: Y[b,h] = relu(max_m(f@w_nn1^T)+b) ----------------
// 2 h-channels per thread (h, h+64): halves ds_read_b128 traffic per FLOP.
__global__ __launch_bounds__(256) void head_kernel(const float* __restrict__ maxh2,
    const int* __restrict__ fidxg, const float* __restrict__ s2g, const float* __restrict__ t2g,
    const float* __restrict__ wnn1, const float* __restrict__ bnn1, float* __restrict__ Y) {
  int b = blockIdx.x >> 2;
  int hc = blockIdx.x & 3;
  __shared__ __align__(16) float ftile[128][CC];
  __shared__ float red2[4][128];
  int hl = threadIdx.x & 63, mseg = threadIdx.x >> 6;   // 64 h-lanes x 4 msegs
  int hA = hc*128 + hl, hB = hA + 64;
  float4 wva[16], wvb[16];
  const float4* wrA = (const float4*)(wnn1 + (size_t)hA*CC);
  const float4* wrB = (const float4*)(wnn1 + (size_t)hB*CC);
#pragma unroll
  for (int q = 0; q < 16; ++q) { wva[q] = wrA[q]; wvb[q] = wrB[q]; }
  float bestA = -FLT_MAX, bestB = -FLT_MAX;
  const int* fb = fidxg + b*MM;
  for (int chunk = 0; chunk < 2; ++chunk) {
    {
      int row = threadIdx.x & 127, chal = threadIdx.x >> 7;
      int fi = fb[chunk*128 + row];
      const float* src = maxh2 + (size_t)(b*NN + fi)*CC;
      for (int ci = chal*32; ci < chal*32+32; ++ci)
        ftile[row][ci] = s2g[ci]*src[ci] + t2g[ci];
    }
    __syncthreads();
    for (int m = mseg*32; m < mseg*32+32; ++m) {
      float accA = 0.f, accB = 0.f;
#pragma unroll
      for (int cq = 0; cq < 16; ++cq) {
        float4 f = *((const float4*)&ftile[m][cq*4]);
        accA = fmaf(f.x, wva[cq].x, accA);
        accA = fmaf(f.y, wva[cq].y, accA);
        accA = fmaf(f.z, wva[cq].z, accA);
        accA = fmaf(f.w, wva[cq].w, accA);
        accB = fmaf(f.x, wvb[cq].x, accB);
        accB = fmaf(f.y, wvb[cq].y, accB);
        accB = fmaf(f.z, wvb[cq].z, accB);
        accB = fmaf(f.w, wvb[cq].w, accB);
      }
      bestA = fmaxf(bestA, accA);
      bestB = fmaxf(bestB, accB);
    }
    __syncthreads();
  }
  red2[mseg][hl] = bestA;
  red2[mseg][64 + hl] = bestB;
  __syncthreads();
  if (threadIdx.x < 128) {
    int hh = hc*128 + threadIdx.x;
    float v = fmaxf(fmaxf(red2[0][threadIdx.x], red2[1][threadIdx.x]),
                    fmaxf(red2[2][threadIdx.x], red2[3][threadIdx.x])) + bnn1[hh];
    Y[(size_t)b*HH + hh] = fmaxf(v, 0.f);
  }
}

// ---------------- BN over batch (two-pass) ----------------
__global__ void bn3_kernel(const float* __restrict__ Y, const float* __restrict__ g,
    const float* __restrict__ be, float* __restrict__ s3, float* __restrict__ t3) {
  int h = blockIdx.x*256 + threadIdx.x;
  float s = 0.f;
  for (int b = 0; b < BB; ++b) s += Y[(size_t)b*HH + h];
  float m = s / (float)BB;
  float v = 0.f;
  for (int b = 0; b < BB; ++b) { float d = Y[(size_t)b*HH + h] - m; v += d*d; }
  v /= (float)BB;
  float sc = g[h] * rsqrtf(v + EPSF);
  s3[h] = sc; t3[h] = be[h] - m*sc;
}

// ---------------- logits + log_softmax ----------------
__global__ __launch_bounds__(256) void logits_kernel(const float* __restrict__ Y,
    const float* __restrict__ s3, const float* __restrict__ t3,
    const float* __restrict__ w4, const float* __restrict__ b4, float* __restrict__ out) {
  int b = blockIdx.x;
  __shared__ float ybn[HH];
  __shared__ float lg[NCLS];
  __shared__ float lse;
  for (int hh = threadIdx.x; hh < HH; hh += 256)
    ybn[hh] = Y[(size_t)b*HH + hh]*s3[hh] + t3[hh];
  __syncthreads();
  if (threadIdx.x < NCLS) {
    int j = threadIdx.x;
    float acc = b4[j];
    const float* wr = w4 + (size_t)j*HH;
    for (int ci = 0; ci < HH; ++ci) acc = fmaf(ybn[ci], wr[ci], acc);
    lg[j] = acc;
  }
  __syncthreads();
  if (threadIdx.x == 0) {
    float mx = -FLT_MAX;
    for (int j = 0; j < NCLS; ++j) mx = fmaxf(mx, lg[j]);
    float s = 0.f;
    for (int j = 0; j < NCLS; ++j) s += expf(lg[j] - mx);
    lse = mx + logf(s);
  }
  __syncthreads();
  if (threadIdx.x < NCLS) out[b*NCLS + threadIdx.x] = lg[threadIdx.x] - lse;
}

extern "C" void kernel_launch(void* const* d_in, const int* in_sizes, int n_in,
                              void* d_out, int out_size, void* d_ws, size_t ws_size,
                              hipStream_t stream) {
  const float* pos  = (const float*)d_in[0];
  const float* w1   = (const float*)d_in[1];
  const float* b1   = (const float*)d_in[2];
  const float* g1   = (const float*)d_in[3];
  const float* be1  = (const float*)d_in[4];
  const float* w2   = (const float*)d_in[5];
  const float* b2   = (const float*)d_in[6];
  const float* g2   = (const float*)d_in[7];
  const float* be2  = (const float*)d_in[8];
  const float* wnn1 = (const float*)d_in[9];
  const float* bnn1 = (const float*)d_in[10];
  const float* gbn2 = (const float*)d_in[11];
  const float* bebn2= (const float*)d_in[12];
  const float* wnn4 = (const float*)d_in[13];
  const float* bnn4 = (const float*)d_in[14];
  float* ws = (float*)d_ws;
  int*   idxg  = (int*)(ws + IDX_OFF);
  float* maxh2 = ws + MAXH2_OFF;
  int*   fidxg = (int*)(ws + FIDX_OFF);
  float* Y     = ws + Y_OFF;
  float* acc1  = ws + ACC_OFF;
  float* acc2  = ws + ACC_OFF + 128;
  unsigned short* w2bf = (unsigned short*)(ws + W2T_OFF);
  float* b2f   = ws + B2F_OFF;
  float* s2    = ws + S2_OFF;
  float* t2    = ws + T2_OFF;
  float* s3    = ws + S3_OFF;
  float* t3    = ws + T3_OFF;
  float* fpsd  = ws + FPSD_OFF;
  int*   fpsc  = (int*)(ws + FPSC_OFF);
  float* outp  = (float*)d_out;

  hipMemsetAsync((void*)(ws + ACC_OFF), 0, 256*sizeof(float), stream);
  knn_fps_kernel<<<BB + BB*32, 256, 0, stream>>>(pos, idxg, fidxg, fpsd, fpsc);
  stats1_kernel<<<BB + BB*16, 256, 0, stream>>>(pos, idxg, w1, b1, acc1, fidxg, fpsd, fpsc);
  fold1_kernel<<<1, 512, 0, stream>>>(acc1, g1, be1, w2, b2, w2bf, b2f);
  conv2_kernel<<<BB + BB*16, 256, 0, stream>>>(pos, idxg, w1, b1, w2bf, b2f, maxh2, acc2, fidxg, fpsd, fpsc);
  fold2_kernel<<<1, 64, 0, stream>>>(acc2, g2, be2, s2, t2);
  head_kernel<<<BB*4, 256, 0, stream>>>(maxh2, fidxg, s2, t2, wnn1, bnn1, Y);
  bn3_kernel<<<2, 256, 0, stream>>>(Y, gbn2, bebn2, s3, t3);
  logits_kernel<<<BB, 256, 0, stream>>>(Y, s3, t3, wnn4, bnn4, outp);
}

// Round 11
// 352.643 us; speedup vs baseline: 1.1602x; 1.1602x over previous
//
#include <hip/hip_runtime.h>
#include <hip/hip_bf16.h>
#include <cfloat>
#include <math.h>

#define BB 64
#define NN 1024
#define KNN 20
#define MM 256
#define CC 64
#define HH 512
#define NCLS 40
#define EPSF 1e-5f
#define CNT1 (BB*NN*KNN)

// FPS phase boundaries: phase1 rounds [1,FPS_R1), phase2 [FPS_R1,FPS_R2),
// phase3 [FPS_R2,MM). Tuned to hide each slice under its host dispatch.
#define FPS_R1 131
#define FPS_R2 176

// workspace offsets (in 4-byte elements)
#define IDX_OFF    0
#define MAXH2_OFF  (IDX_OFF + BB*NN*KNN)      // int idx then floats
#define FIDX_OFF   (MAXH2_OFF + BB*NN*CC)
#define Y_OFF      (FIDX_OFF + BB*MM)
#define ACC_OFF    (Y_OFF + BB*HH)            // 256 floats zeroed: sum1[64],sumsq1[64],sum2[64],sumsq2[64]
#define W2T_OFF    (ACC_OFF + 256)            // w2' bf16 B-frags (2048 ushorts) + b2f
#define B2F_OFF    (W2T_OFF + CC*CC)
#define FPSD_OFF   (B2F_OFF + CC)             // BB*NN floats: FPS dist state
#define FPSC_OFF   (FPSD_OFF + BB*NN)         // BB ints: FPS cur state

typedef __attribute__((ext_vector_type(8)))  short short8;
typedef __attribute__((ext_vector_type(16))) float f32x16;

static __device__ __forceinline__ unsigned short f2bf(float f) {
  unsigned u = __float_as_uint(f);
  unsigned r = (u + 0x7fffu + ((u >> 16) & 1u)) >> 16;   // RNE
  return (unsigned short)r;
}

// ---------------- FPS phase (single wave; caller: threadIdx.x < 64) ----------------
// All-float reduction (dist >= +0 so fmaxf == bit-max, float eq == bit eq);
// bit-exact vs numpy (max dist, ties -> smallest index). State checkpointed
// to global between phases.
static __device__ __forceinline__ void fps_phase(
    const float* sx, const float* sy, const float* sz,   // LDS, NN each
    float* fpsd, int* fpsc, int* fidxg, int b, int mStart, int mEnd) {
  int lane = threadIdx.x;
  float lx[16], ly[16], lz[16], dist[16];
#pragma unroll
  for (int q = 0; q < 16; ++q) {
    int j = q*64 + lane;
    lx[q] = sx[j]; ly[q] = sy[j]; lz[q] = sz[j];
  }
  int cur;
  if (mStart <= 1) {
#pragma unroll
    for (int q = 0; q < 16; ++q) dist[q] = 1e38f;
    if (lane == 0) fidxg[b*MM] = 0;
    cur = 0;
  } else {
#pragma unroll
    for (int q = 0; q < 16; ++q) dist[q] = fpsd[b*NN + q*64 + lane];
    cur = fpsc[b];
  }
  for (int m = mStart; m < mEnd; ++m) {
    float cpx = sx[cur], cpy = sy[cur], cpz = sz[cur];   // uniform LDS broadcast
#pragma unroll
    for (int q = 0; q < 16; ++q) {
      float dx = __fsub_rn(lx[q], cpx);
      float dy = __fsub_rn(ly[q], cpy);
      float dz = __fsub_rn(lz[q], cpz);
      float dd = __fadd_rn(__fadd_rn(__fmul_rn(dx,dx), __fmul_rn(dy,dy)), __fmul_rn(dz,dz));
      dist[q] = fminf(dist[q], dd);
    }
    float t8[8];
#pragma unroll
    for (int q = 0; q < 8; ++q) t8[q] = fmaxf(dist[q], dist[q + 8]);
#pragma unroll
    for (int q = 0; q < 4; ++q) t8[q] = fmaxf(t8[q], t8[q + 4]);
    float r = fmaxf(fmaxf(t8[0], t8[1]), fmaxf(t8[2], t8[3]));
#define FPS_VMAX_STEP(C) { \
    int tt = __builtin_amdgcn_update_dpp(__float_as_int(r), __float_as_int(r), (C), 0xf, 0xf, false); \
    r = fmaxf(r, __int_as_float(tt)); }
    FPS_VMAX_STEP(0x111)   // row_shr:1
    FPS_VMAX_STEP(0x112)   // row_shr:2
    FPS_VMAX_STEP(0x114)   // row_shr:4
    FPS_VMAX_STEP(0x118)   // row_shr:8
    FPS_VMAX_STEP(0x142)   // row_bcast:15
    FPS_VMAX_STEP(0x143)   // row_bcast:31
#undef FPS_VMAX_STEP
    float wmax = __int_as_float(__builtin_amdgcn_readlane(__float_as_int(r), 63));
    unsigned ci = 0xFFFFFFFFu;
#pragma unroll
    for (int q = 15; q >= 0; --q)
      if (dist[q] == wmax) ci = (unsigned)(q*64 + lane);
#define FPS_IMIN_STEP(C) { \
    unsigned tt = (unsigned)__builtin_amdgcn_update_dpp((int)ci, (int)ci, (C), 0xf, 0xf, false); \
    ci = (tt < ci) ? tt : ci; }
    FPS_IMIN_STEP(0x111)
    FPS_IMIN_STEP(0x112)
    FPS_IMIN_STEP(0x114)
    FPS_IMIN_STEP(0x118)
    FPS_IMIN_STEP(0x142)
    FPS_IMIN_STEP(0x143)
#undef FPS_IMIN_STEP
    cur = (int)(unsigned)__builtin_amdgcn_readlane((int)ci, 63);
    if (lane == 0) fidxg[b*MM + m] = cur;
  }
  if (mEnd < MM) {   // checkpoint
#pragma unroll
    for (int q = 0; q < 16; ++q) fpsd[b*NN + q*64 + lane] = dist[q];
    if (lane == 0) fpsc[b] = cur;
  }
}

// ---------------- fused FPS(phase1) + kNN ----------------
// blocks [0, BB): FPS rounds [1, FPS_R1).
// blocks [BB, BB + BB*32): kNN, one wave per 8 queries — the R8-proven
// single-query structure (56 VGPR; pairwise interleave regressed via
// occupancy, R9 post-mortem).
__global__ __launch_bounds__(256) void knn_fps_kernel(const float* __restrict__ pos,
                                                      int* __restrict__ idxg,
                                                      int* __restrict__ fidxg,
                                                      float* __restrict__ fpsd,
                                                      int* __restrict__ fpsc) {
  __shared__ float4 pj[NN];
  if (blockIdx.x >= BB) {
    // ---------------- kNN branch ----------------
    int blk = blockIdx.x - BB;
    int b  = blk >> 5;   // cloud
    int nb = blk & 31;   // 32-point segment of the cloud
    const float* pb = pos + (size_t)b * NN * 3;
    for (int i = threadIdx.x; i < NN; i += 256) {
      float x = pb[i*3+0], y = pb[i*3+1], z = pb[i*3+2];
      pj[i] = make_float4(x, y, z, (x*x + y*y) + z*z);
    }
    __syncthreads();
    int lane = threadIdx.x & 63;
    int wv   = threadIdx.x >> 6;
    unsigned long long lmask_lt = (1ULL << lane) - 1ULL;

    for (int t = 0; t < 8; ++t) {
      int i = nb*32 + wv*8 + t;        // query point (wave-uniform)
      float4 pi = pj[i];               // LDS broadcast
      unsigned u[16];
#pragma unroll
      for (int q = 0; q < 16; ++q) {
        int j = q*64 + lane;
        float4 pw = pj[j];
        float d = pi.w + pw.w - 2.0f*(pi.x*pw.x + pi.y*pw.y + pi.z*pw.z);
        unsigned bits = __float_as_uint(d);
        bits = (bits & 0x80000000u) ? ~bits : (bits | 0x80000000u);
        if (j == i) bits = 0xFFFFFFFFu;   // self excluded (diag = +inf)
        u[q] = bits;
      }
      // per-lane min of 16, then wave-min and wave-max-of-lane-mins via DPP
      unsigned lmin = u[0];
#pragma unroll
      for (int q = 1; q < 16; ++q) lmin = (u[q] < lmin) ? u[q] : lmin;
      unsigned rmin = lmin, rmax = lmin;
#define KNN_DPP_STEP(C) { \
      unsigned t1 = (unsigned)__builtin_amdgcn_update_dpp((int)rmin, (int)rmin, (C), 0xf, 0xf, false); \
      unsigned t2 = (unsigned)__builtin_amdgcn_update_dpp((int)rmax, (int)rmax, (C), 0xf, 0xf, false); \
      rmin = (t1 < rmin) ? t1 : rmin; rmax = (t2 > rmax) ? t2 : rmax; }
      KNN_DPP_STEP(0x111)   // row_shr:1
      KNN_DPP_STEP(0x112)   // row_shr:2
      KNN_DPP_STEP(0x114)   // row_shr:4
      KNN_DPP_STEP(0x118)   // row_shr:8
      KNN_DPP_STEP(0x142)   // row_bcast:15
      KNN_DPP_STEP(0x143)   // row_bcast:31
#undef KNN_DPP_STEP
      unsigned plo = ((unsigned)__builtin_amdgcn_readlane((int)rmin, 63)) >> 16;
      unsigned phi = ((unsigned)__builtin_amdgcn_readlane((int)rmax, 63)) >> 16;
      // narrowed binary search; carry the count measured at the final phi
      int cntHi = -1;
      while (plo < phi) {                 // wave-uniform
        unsigned pmid = (plo + phi) >> 1;
        unsigned tmid = (pmid << 16) | 0xFFFFu;
        int cnt = 0;
#pragma unroll
        for (int q = 0; q < 16; ++q)
          cnt += (int)__popcll(__ballot(u[q] <= tmid));
        if (cnt >= KNN) { phi = pmid; cntHi = cnt; } else plo = pmid + 1;
      }
      unsigned tstar = (phi << 16) | 0xFFFFu;  // bucket top
      unsigned bbase = phi << 16;              // bucket base
      int* op = idxg + (size_t)(b*NN + i) * KNN;
      if (cntHi < 0) {   // phi never measured (rare): recount
        cntHi = 0;
#pragma unroll
        for (int q = 0; q < 16; ++q)
          cntHi += (int)__popcll(__ballot(u[q] <= tstar));
      }
      if (cntHi == KNN) {
        // exact set: emit all <= tstar (index order; set-equivalent)
        int base = 0;
#pragma unroll
        for (int q = 0; q < 16; ++q) {
          bool pred = (u[q] <= tstar);
          unsigned long long mask = __ballot((int)pred);
          if (pred) op[base + (int)__popcll(mask & lmask_lt)] = q*64 + lane;
          base += (int)__popcll(mask);
        }
      } else {
        // slow path: refine low 16 bits -> exact 20th value xstar
        unsigned lo2 = bbase, hi2 = tstar;
        while (lo2 < hi2) {
          unsigned mid = lo2 + ((hi2 - lo2) >> 1);
          int cnt = 0;
#pragma unroll
          for (int q = 0; q < 16; ++q)
            cnt += (int)__popcll(__ballot(u[q] <= mid));
          if (cnt >= KNN) hi2 = mid; else lo2 = mid + 1;
        }
        unsigned xstar = lo2;
        int base = 0;
#pragma unroll
        for (int q = 0; q < 16; ++q) {
          bool pred = (u[q] < xstar);
          unsigned long long mask = __ballot((int)pred);
          if (pred) op[base + (int)__popcll(mask & lmask_lt)] = q*64 + lane;
          base += (int)__popcll(mask);
        }
        for (int q = 0; q < 16 && base < KNN; ++q) {  // ties, ascending index
          bool pred = (u[q] == xstar);
          unsigned long long mask = __ballot((int)pred);
          if (pred) {
            int pos_ = base + (int)__popcll(mask & lmask_lt);
            if (pos_ < KNN) op[pos_] = q*64 + lane;
          }
          base += (int)__popcll(mask);
        }
      }
    }
  } else {
    // ---------------- FPS phase 1 ----------------
    int b = blockIdx.x;
    float* base = (float*)pj;            // reuse 16 KB as 3 x NN floats
    float* sx = base; float* sy = base + NN; float* sz = base + 2*NN;
    const float* pb = pos + (size_t)b * NN * 3;
    for (int i = threadIdx.x; i < NN; i += 256) {
      sx[i] = pb[i*3+0]; sy[i] = pb[i*3+1]; sz[i] = pb[i*3+2];
    }
    __syncthreads();
    if (threadIdx.x >= 64) return;
    fps_phase(sx, sy, sz, fpsd, fpsc, fidxg, b, 1, FPS_R1);
  }
}

// ---------------- stats of h1 + FPS phase 2 ----------------
__global__ __launch_bounds__(256) void stats1_kernel(const float* __restrict__ pos,
    const int* __restrict__ idxg, const float* __restrict__ w1,
    const float* __restrict__ b1, float* __restrict__ acc,
    int* __restrict__ fidxg, float* __restrict__ fpsd, int* __restrict__ fpsc) {
  __shared__ float px[NN], py[NN], pz[NN];
  __shared__ float relx[4][KNN], rely[4][KNN], relz[4][KNN];
  __shared__ float red[4][CC];
  if (blockIdx.x < BB) {
    // ---------------- FPS phase 2 ----------------
    int b = blockIdx.x;
    const float* pb = pos + (size_t)b*NN*3;
    for (int i = threadIdx.x; i < NN; i += 256) {
      px[i] = pb[i*3+0]; py[i] = pb[i*3+1]; pz[i] = pb[i*3+2];
    }
    __syncthreads();
    if (threadIdx.x >= 64) return;
    fps_phase(px, py, pz, fpsd, fpsc, fidxg, b, FPS_R1, FPS_R2);
    return;
  }
  int blk = blockIdx.x - BB;
  int b = blk >> 4;
  int nb = blk & 15;
  const float* pb = pos + (size_t)b*NN*3;
  for (int i = threadIdx.x; i < NN; i += 256) {
    px[i] = pb[i*3+0]; py[i] = pb[i*3+1]; pz[i] = pb[i*3+2];
  }
  int c = threadIdx.x & 63, w = threadIdx.x >> 6;
  float w1x = w1[c*3+0], w1y = w1[c*3+1], w1z = w1[c*3+2], b1c = b1[c];
  float s = 0.f, ss = 0.f;
  __syncthreads();
  for (int it = 0; it < 16; ++it) {
    int n0 = nb*64 + it*4;
    if (threadIdx.x < 80) {
      int wv = threadIdx.x / KNN, k = threadIdx.x % KNN;
      int n = n0 + wv;
      int j = idxg[(size_t)(b*NN + n)*KNN + k];
      relx[wv][k] = px[j] - px[n];
      rely[wv][k] = py[j] - py[n];
      relz[wv][k] = pz[j] - pz[n];
    }
    __syncthreads();
#pragma unroll
    for (int k = 0; k < KNN; ++k) {
      float h = fmaxf(relx[w][k]*w1x + rely[w][k]*w1y + relz[w][k]*w1z + b1c, 0.f);
      s += h; ss += h*h;
    }
    __syncthreads();
  }
  red[w][c] = s; __syncthreads();
  if (w == 0) atomicAdd(&acc[c], red[0][c]+red[1][c]+red[2][c]+red[3][c]);
  __syncthreads();
  red[w][c] = ss; __syncthreads();
  if (w == 0) atomicAdd(&acc[64+c], red[0][c]+red[1][c]+red[2][c]+red[3][c]);
}

// ---------------- fold BN1 into w2 (bf16 B-fragment layout) ----------------
__global__ void fold1_kernel(const float* __restrict__ acc, const float* __restrict__ g1,
    const float* __restrict__ be1, const float* __restrict__ w2, const float* __restrict__ b2,
    unsigned short* __restrict__ w2bf, float* __restrict__ b2f) {
  __shared__ float s1[CC], t1[CC];
  int tid = threadIdx.x;  // 512 threads
  if (tid < CC) {
    float cnt = (float)CNT1;
    float m = acc[tid] / cnt;
    float v = acc[64+tid] / cnt - m*m;
    float sc = g1[tid] * rsqrtf(v + EPSF);
    s1[tid] = sc; t1[tid] = be1[tid] - m*sc;
  }
  __syncthreads();
  int frag = tid >> 6;        // 0..7  (nt = frag>>2, ks = frag&3)
  int lane = tid & 63;
  int nt = frag >> 2, ks = frag & 3;
  int cout = nt*32 + (lane & 31);
  int cin0 = ks*16 + (lane >> 5)*8;
  for (int j = 0; j < 8; ++j) {
    int cin = cin0 + j;
    w2bf[((size_t)frag*64 + lane)*8 + j] = f2bf(w2[cout*CC + cin] * s1[cin]);
  }
  if (tid < CC) {
    float accb = b2[tid];
    for (int ci = 0; ci < CC; ++ci) accb += t1[ci]*w2[tid*CC + ci];
    b2f[tid] = accb;
  }
}

// ---------------- conv2 via MFMA + FPS phase 3 ----------------
__global__ __launch_bounds__(256, 4) void conv2_kernel(const float* __restrict__ pos,
    const int* __restrict__ idxg, const float* __restrict__ w1, const float* __restrict__ b1,
    const unsigned short* __restrict__ w2bf, const float* __restrict__ b2fg,
    float* __restrict__ maxh2, float* __restrict__ acc2,
    int* __restrict__ fidxg, float* __restrict__ fpsd, int* __restrict__ fpsc) {
  __shared__ float px[NN], py[NN], pz[NN];
  __shared__ float4 relw[4][KNN];
  __shared__ __align__(16) unsigned short h1s[4][2112];  // 8 groups * 264 ushorts
  __shared__ float redbuf[4][2*CC];
  if (blockIdx.x < BB) {
    // ---------------- FPS phase 3 ----------------
    int b = blockIdx.x;
    const float* pb = pos + (size_t)b*NN*3;
    for (int i = threadIdx.x; i < NN; i += 256) {
      px[i] = pb[i*3+0]; py[i] = pb[i*3+1]; pz[i] = pb[i*3+2];
    }
    __syncthreads();
    if (threadIdx.x >= 64) return;
    fps_phase(px, py, pz, fpsd, fpsc, fidxg, b, FPS_R2, MM);
    return;
  }
  int blk = blockIdx.x - BB;
  int b = blk >> 4;
  int nb = blk & 15;
  const float* pb = pos + (size_t)b*NN*3;
  for (int i = threadIdx.x; i < NN; i += 256) {
    px[i] = pb[i*3+0]; py[i] = pb[i*3+1]; pz[i] = pb[i*3+2];
  }
  int lane = threadIdx.x & 63, w = threadIdx.x >> 6;
  int half = lane >> 5, l31 = lane & 31;
  short8 Bf[2][4];
#pragma unroll
  for (int nt = 0; nt < 2; ++nt)
#pragma unroll
    for (int ks = 0; ks < 4; ++ks)
      Bf[nt][ks] = *(const short8*)&w2bf[((size_t)(nt*4+ks)*64 + lane)*8];
  float b2o0 = b2fg[l31], b2o1 = b2fg[32 + l31];
  float w1x = w1[lane*3+0], w1y = w1[lane*3+1], w1z = w1[lane*3+2], b1c = b1[lane];
  unsigned short* hw = h1s[w];
  {
    short8 zz = {0,0,0,0,0,0,0,0};
    for (int z = lane; z < 96; z += 64) {
      int g = z / 12, r = 20 + z % 12;
      *(short8*)&hw[g*264 + r*8] = zz;
    }
  }
  float sA = 0.f, ssA = 0.f, sB = 0.f, ssB = 0.f;
  __syncthreads();
  for (int t = 0; t < 16; ++t) {
    int n = nb*64 + w*16 + t;
    if (lane < KNN) {
      int j = idxg[(size_t)(b*NN + n)*KNN + lane];
      relw[w][lane] = make_float4(px[j]-px[n], py[j]-py[n], pz[j]-pz[n], 0.f);
    }
    int gbase = (lane >> 3)*264 + (lane & 7);
#pragma unroll
    for (int k = 0; k < KNN; ++k) {
      float4 r4 = relw[w][k];   // wave-uniform broadcast read
      float h = fmaxf(fmaf(r4.x, w1x, fmaf(r4.y, w1y, fmaf(r4.z, w1z, b1c))), 0.f);
      hw[gbase + k*8] = f2bf(h);
    }
    f32x16 acc0 = {}; f32x16 acc1 = {};
#pragma unroll
    for (int ks = 0; ks < 4; ++ks) {
      short8 A = *(const short8*)&hw[(ks*2 + half)*264 + l31*8];
      acc0 = __builtin_amdgcn_mfma_f32_32x32x16_bf16(A, Bf[0][ks], acc0, 0, 0, 0);
      acc1 = __builtin_amdgcn_mfma_f32_32x32x16_bf16(A, Bf[1][ks], acc1, 0, 0, 0);
    }
    float mx0 = 0.f, mx1 = 0.f;
#pragma unroll
    for (int reg = 0; reg < 8; ++reg) {
      float v0 = fmaxf(acc0[reg] + b2o0, 0.f);
      float v1 = fmaxf(acc1[reg] + b2o1, 0.f);
      sA += v0; ssA += v0*v0; sB += v1; ssB += v1*v1;
      mx0 = fmaxf(mx0, v0); mx1 = fmaxf(mx1, v1);
    }
    if (half == 0) {
#pragma unroll
      for (int reg = 8; reg < 12; ++reg) {
        float v0 = fmaxf(acc0[reg] + b2o0, 0.f);
        float v1 = fmaxf(acc1[reg] + b2o1, 0.f);
        sA += v0; ssA += v0*v0; sB += v1; ssB += v1*v1;
        mx0 = fmaxf(mx0, v0); mx1 = fmaxf(mx1, v1);
      }
    }
    mx0 = fmaxf(mx0, __shfl_xor(mx0, 32, 64));
    mx1 = fmaxf(mx1, __shfl_xor(mx1, 32, 64));
    if (half == 0) {
      float* mp = maxh2 + (size_t)(b*NN + n)*CC;
      mp[l31] = mx0; mp[32 + l31] = mx1;
    }
  }
  sA += __shfl_xor(sA, 32, 64); ssA += __shfl_xor(ssA, 32, 64);
  sB += __shfl_xor(sB, 32, 64); ssB += __shfl_xor(ssB, 32, 64);
  if (half == 0) { redbuf[w][l31] = sA; redbuf[w][32 + l31] = sB; }
  __syncthreads();
  if (w == 0) atomicAdd(&acc2[lane], redbuf[0][lane]+redbuf[1][lane]+redbuf[2][lane]+redbuf[3][lane]);
  __syncthreads();
  if (half == 0) { redbuf[w][l31] = ssA; redbuf[w][32 + l31] = ssB; }
  __syncthreads();
  if (w == 0) atomicAdd(&acc2[64+lane], redbuf[0][lane]+redbuf[1][lane]+redbuf[2][lane]+redbuf[3][lane]);
}

// ---------------- head: Y[b,h] = relu(max_m(f@w_nn1^T)+b) ----------------
// fold2 fused: s2/t2 computed per block from acc2 (bit-identical arithmetic).
// 2 h-channels per thread (h, h+64): halves ds_read_b128 traffic per FLOP.
__global__ __launch_bounds__(256) void head_kernel(const float* __restrict__ maxh2,
    const int* __restrict__ fidxg, const float* __restrict__ acc2,
    const float* __restrict__ g2, const float* __restrict__ be2,
    const float* __restrict__ wnn1, const float* __restrict__ bnn1, float* __restrict__ Y) {
  int b = blockIdx.x >> 2;
  int hc = blockIdx.x & 3;
  __shared__ __align__(16) float ftile[128][CC];
  __shared__ float red2[4][128];
  __shared__ float s2s[CC], t2s[CC];
  if (threadIdx.x < CC) {
    int c = threadIdx.x;
    float cnt = (float)CNT1;
    float m = acc2[c]/cnt;
    float v = acc2[64+c]/cnt - m*m;
    float sc = g2[c]*rsqrtf(v+EPSF);
    s2s[c] = sc;
    t2s[c] = be2[c] - m*sc;
  }
  int hl = threadIdx.x & 63, mseg = threadIdx.x >> 6;   // 64 h-lanes x 4 msegs
  int hA = hc*128 + hl, hB = hA + 64;
  float4 wva[16], wvb[16];
  const float4* wrA = (const float4*)(wnn1 + (size_t)hA*CC);
  const float4* wrB = (const float4*)(wnn1 + (size_t)hB*CC);
#pragma unroll
  for (int q = 0; q < 16; ++q) { wva[q] = wrA[q]; wvb[q] = wrB[q]; }
  float bestA = -FLT_MAX, bestB = -FLT_MAX;
  const int* fb = fidxg + b*MM;
  __syncthreads();
  for (int chunk = 0; chunk < 2; ++chunk) {
    {
      int row = threadIdx.x & 127, chal = threadIdx.x >> 7;
      int fi = fb[chunk*128 + row];
      const float* src = maxh2 + (size_t)(b*NN + fi)*CC;
      for (int ci = chal*32; ci < chal*32+32; ++ci)
        ftile[row][ci] = s2s[ci]*src[ci] + t2s[ci];
    }
    __syncthreads();
    for (int m = mseg*32; m < mseg*32+32; ++m) {
      float accA = 0.f, accB = 0.f;
#pragma unroll
      for (int cq = 0; cq < 16; ++cq) {
        float4 f = *((const float4*)&ftile[m][cq*4]);
        accA = fmaf(f.x, wva[cq].x, accA);
        accA = fmaf(f.y, wva[cq].y, accA);
        accA = fmaf(f.z, wva[cq].z, accA);
        accA = fmaf(f.w, wva[cq].w, accA);
        accB = fmaf(f.x, wvb[cq].x, accB);
        accB = fmaf(f.y, wvb[cq].y, accB);
        accB = fmaf(f.z, wvb[cq].z, accB);
        accB = fmaf(f.w, wvb[cq].w, accB);
      }
      bestA = fmaxf(bestA, accA);
      bestB = fmaxf(bestB, accB);
    }
    __syncthreads();
  }
  red2[mseg][hl] = bestA;
  red2[mseg][64 + hl] = bestB;
  __syncthreads();
  if (threadIdx.x < 128) {
    int hh = hc*128 + threadIdx.x;
    float v = fmaxf(fmaxf(red2[0][threadIdx.x], red2[1][threadIdx.x]),
                    fmaxf(red2[2][threadIdx.x], red2[3][threadIdx.x])) + bnn1[hh];
    Y[(size_t)b*HH + hh] = fmaxf(v, 0.f);
  }
}

// ---------------- logits + log_softmax (bn3 fused per block) ----------------
__global__ __launch_bounds__(256) void logits_kernel(const float* __restrict__ Y,
    const float* __restrict__ g3, const float* __restrict__ be3,
    const float* __restrict__ w4, const float* __restrict__ b4, float* __restrict__ out) {
  int b = blockIdx.x;
  __shared__ float ybn[HH];
  __shared__ float s3s[HH], t3s[HH];
  __shared__ float lg[NCLS];
  __shared__ float lse;
  // bn3 recomputed per block (bit-identical to the old bn3_kernel ordering)
  for (int h = threadIdx.x; h < HH; h += 256) {
    float s = 0.f;
    for (int bb = 0; bb < BB; ++bb) s += Y[(size_t)bb*HH + h];
    float m = s / (float)BB;
    float v = 0.f;
    for (int bb = 0; bb < BB; ++bb) { float d = Y[(size_t)bb*HH + h] - m; v += d*d; }
    v /= (float)BB;
    float sc = g3[h] * rsqrtf(v + EPSF);
    s3s[h] = sc; t3s[h] = be3[h] - m*sc;
  }
  __syncthreads();
  for (int hh = threadIdx.x; hh < HH; hh += 256)
    ybn[hh] = Y[(size_t)b*HH + hh]*s3s[hh] + t3s[hh];
  __syncthreads();
  if (threadIdx.x < NCLS) {
    int j = threadIdx.x;
    float acc = b4[j];
    const float* wr = w4 + (size_t)j*HH;
    for (int ci = 0; ci < HH; ++ci) acc = fmaf(ybn[ci], wr[ci], acc);
    lg[j] = acc;
  }
  __syncthreads();
  if (threadIdx.x == 0) {
    float mx = -FLT_MAX;
    for (int j = 0; j < NCLS; ++j) mx = fmaxf(mx, lg[j]);
    float s = 0.f;
    for (int j = 0; j < NCLS; ++j) s += expf(lg[j] - mx);
    lse = mx + logf(s);
  }
  __syncthreads();
  if (threadIdx.x < NCLS) out[b*NCLS + threadIdx.x] = lg[threadIdx.x] - lse;
}

extern "C" void kernel_launch(void* const* d_in, const int* in_sizes, int n_in,
                              void* d_out, int out_size, void* d_ws, size_t ws_size,
                              hipStream_t stream) {
  const float* pos  = (const float*)d_in[0];
  const float* w1   = (const float*)d_in[1];
  const float* b1   = (const float*)d_in[2];
  const float* g1   = (const float*)d_in[3];
  const float* be1  = (const float*)d_in[4];
  const float* w2   = (const float*)d_in[5];
  const float* b2   = (const float*)d_in[6];
  const float* g2   = (const float*)d_in[7];
  const float* be2  = (const float*)d_in[8];
  const float* wnn1 = (const float*)d_in[9];
  const float* bnn1 = (const float*)d_in[10];
  const float* gbn2 = (const float*)d_in[11];
  const float* bebn2= (const float*)d_in[12];
  const float* wnn4 = (const float*)d_in[13];
  const float* bnn4 = (const float*)d_in[14];
  float* ws = (float*)d_ws;
  int*   idxg  = (int*)(ws + IDX_OFF);
  float* maxh2 = ws + MAXH2_OFF;
  int*   fidxg = (int*)(ws + FIDX_OFF);
  float* Y     = ws + Y_OFF;
  float* acc1  = ws + ACC_OFF;
  float* acc2  = ws + ACC_OFF + 128;
  unsigned short* w2bf = (unsigned short*)(ws + W2T_OFF);
  float* b2f   = ws + B2F_OFF;
  float* fpsd  = ws + FPSD_OFF;
  int*   fpsc  = (int*)(ws + FPSC_OFF);
  float* outp  = (float*)d_out;

  hipMemsetAsync((void*)(ws + ACC_OFF), 0, 256*sizeof(float), stream);
  knn_fps_kernel<<<BB + BB*32, 256, 0, stream>>>(pos, idxg, fidxg, fpsd, fpsc);
  stats1_kernel<<<BB + BB*16, 256, 0, stream>>>(pos, idxg, w1, b1, acc1, fidxg, fpsd, fpsc);
  fold1_kernel<<<1, 512, 0, stream>>>(acc1, g1, be1, w2, b2, w2bf, b2f);
  conv2_kernel<<<BB + BB*16, 256, 0, stream>>>(pos, idxg, w1, b1, w2bf, b2f, maxh2, acc2, fidxg, fpsd, fpsc);
  head_kernel<<<BB*4, 256, 0, stream>>>(maxh2, fidxg, acc2, g2, be2, wnn1, bnn1, Y);
  logits_kernel<<<BB, 256, 0, stream>>>(Y, gbn2, bebn2, wnn4, bnn4, outp);
}

// Round 12
// 336.226 us; speedup vs baseline: 1.2169x; 1.0488x over previous
//
#include <hip/hip_runtime.h>
#include <hip/hip_bf16.h>
#include <cfloat>
#include <math.h>

#define BB 64
#define NN 1024
#define KNN 20
#define MM 256
#define CC 64
#define HH 512
#define NCLS 40
#define EPSF 1e-5f
#define CNT1 (BB*NN*KNN)

// FPS phase boundaries: phase1 rounds [1,FPS_R1) under K1 (knn+stats),
// phase2 [FPS_R1,MM) under conv2.
#define FPS_R1 201

// workspace offsets (in 4-byte elements)
#define IDX_OFF    0
#define MAXH2_OFF  (IDX_OFF + BB*NN*KNN)      // int idx then floats
#define FIDX_OFF   (MAXH2_OFF + BB*NN*CC)
#define Y_OFF      (FIDX_OFF + BB*MM)
#define ACC_OFF    (Y_OFF + BB*HH)            // 256 floats zeroed: sum1[64],sumsq1[64],sum2[64],sumsq2[64]
#define W2T_OFF    (ACC_OFF + 256)            // w2' bf16 B-frags (2048 ushorts) + b2f
#define B2F_OFF    (W2T_OFF + CC*CC)
#define FPSD_OFF   (B2F_OFF + CC)             // BB*NN floats: FPS dist state
#define FPSC_OFF   (FPSD_OFF + BB*NN)         // BB ints: FPS cur state

typedef __attribute__((ext_vector_type(8)))  short short8;
typedef __attribute__((ext_vector_type(16))) float f32x16;

static __device__ __forceinline__ unsigned short f2bf(float f) {
  unsigned u = __float_as_uint(f);
  unsigned r = (u + 0x7fffu + ((u >> 16) & 1u)) >> 16;   // RNE
  return (unsigned short)r;
}

// ---------------- FPS phase (single wave; caller: threadIdx.x < 64) ----------------
// All-float reduction (dist >= +0 so fmaxf == bit-max, float eq == bit eq);
// bit-exact vs numpy (max dist, ties -> smallest index). State checkpointed
// to global between phases.
static __device__ __forceinline__ void fps_phase(
    const float* sx, const float* sy, const float* sz,   // LDS, NN each
    float* fpsd, int* fpsc, int* fidxg, int b, int mStart, int mEnd) {
  int lane = threadIdx.x;
  float lx[16], ly[16], lz[16], dist[16];
#pragma unroll
  for (int q = 0; q < 16; ++q) {
    int j = q*64 + lane;
    lx[q] = sx[j]; ly[q] = sy[j]; lz[q] = sz[j];
  }
  int cur;
  if (mStart <= 1) {
#pragma unroll
    for (int q = 0; q < 16; ++q) dist[q] = 1e38f;
    if (lane == 0) fidxg[b*MM] = 0;
    cur = 0;
  } else {
#pragma unroll
    for (int q = 0; q < 16; ++q) dist[q] = fpsd[b*NN + q*64 + lane];
    cur = fpsc[b];
  }
  for (int m = mStart; m < mEnd; ++m) {
    float cpx = sx[cur], cpy = sy[cur], cpz = sz[cur];   // uniform LDS broadcast
#pragma unroll
    for (int q = 0; q < 16; ++q) {
      float dx = __fsub_rn(lx[q], cpx);
      float dy = __fsub_rn(ly[q], cpy);
      float dz = __fsub_rn(lz[q], cpz);
      float dd = __fadd_rn(__fadd_rn(__fmul_rn(dx,dx), __fmul_rn(dy,dy)), __fmul_rn(dz,dz));
      dist[q] = fminf(dist[q], dd);
    }
    float t8[8];
#pragma unroll
    for (int q = 0; q < 8; ++q) t8[q] = fmaxf(dist[q], dist[q + 8]);
#pragma unroll
    for (int q = 0; q < 4; ++q) t8[q] = fmaxf(t8[q], t8[q + 4]);
    float r = fmaxf(fmaxf(t8[0], t8[1]), fmaxf(t8[2], t8[3]));
#define FPS_VMAX_STEP(C) { \
    int tt = __builtin_amdgcn_update_dpp(__float_as_int(r), __float_as_int(r), (C), 0xf, 0xf, false); \
    r = fmaxf(r, __int_as_float(tt)); }
    FPS_VMAX_STEP(0x111)   // row_shr:1
    FPS_VMAX_STEP(0x112)   // row_shr:2
    FPS_VMAX_STEP(0x114)   // row_shr:4
    FPS_VMAX_STEP(0x118)   // row_shr:8
    FPS_VMAX_STEP(0x142)   // row_bcast:15
    FPS_VMAX_STEP(0x143)   // row_bcast:31
#undef FPS_VMAX_STEP
    float wmax = __int_as_float(__builtin_amdgcn_readlane(__float_as_int(r), 63));
    unsigned ci = 0xFFFFFFFFu;
#pragma unroll
    for (int q = 15; q >= 0; --q)
      if (dist[q] == wmax) ci = (unsigned)(q*64 + lane);
#define FPS_IMIN_STEP(C) { \
    unsigned tt = (unsigned)__builtin_amdgcn_update_dpp((int)ci, (int)ci, (C), 0xf, 0xf, false); \
    ci = (tt < ci) ? tt : ci; }
    FPS_IMIN_STEP(0x111)
    FPS_IMIN_STEP(0x112)
    FPS_IMIN_STEP(0x114)
    FPS_IMIN_STEP(0x118)
    FPS_IMIN_STEP(0x142)
    FPS_IMIN_STEP(0x143)
#undef FPS_IMIN_STEP
    cur = (int)(unsigned)__builtin_amdgcn_readlane((int)ci, 63);
    if (lane == 0) fidxg[b*MM + m] = cur;
  }
  if (mEnd < MM) {   // checkpoint
#pragma unroll
    for (int q = 0; q < 16; ++q) fpsd[b*NN + q*64 + lane] = dist[q];
    if (lane == 0) fpsc[b] = cur;
  }
}

// ---------------- fused FPS(phase1) + kNN + BN1 stats ----------------
// blocks [0, BB): FPS rounds [1, FPS_R1).
// blocks [BB, BB + BB*32): kNN (R8-proven single-query structure) with the
// h1 = relu(rel@w1+b1) BN1-stats epilogue fused in: the 20 emitted indices
// are mirrored to a per-wave LDS buffer, then lane=channel accumulates
// s/ss over the wave's 8 queries x 20 neighbors -> block reduce -> atomics.
// This eliminates the entire stats1 dispatch (same pj data, same indices).
__global__ __launch_bounds__(256) void knn_fps_kernel(const float* __restrict__ pos,
                                                      int* __restrict__ idxg,
                                                      int* __restrict__ fidxg,
                                                      float* __restrict__ fpsd,
                                                      int* __restrict__ fpsc,
                                                      const float* __restrict__ w1,
                                                      const float* __restrict__ b1,
                                                      float* __restrict__ acc1) {
  __shared__ float4 pj[NN];
  __shared__ int nbrs[4][KNN];
  __shared__ float red[4][CC];
  if (blockIdx.x >= BB) {
    // ---------------- kNN + stats branch ----------------
    int blk = blockIdx.x - BB;
    int b  = blk >> 5;   // cloud
    int nb = blk & 31;   // 32-point segment of the cloud
    const float* pb = pos + (size_t)b * NN * 3;
    for (int i = threadIdx.x; i < NN; i += 256) {
      float x = pb[i*3+0], y = pb[i*3+1], z = pb[i*3+2];
      pj[i] = make_float4(x, y, z, (x*x + y*y) + z*z);
    }
    __syncthreads();
    int lane = threadIdx.x & 63;
    int wv   = threadIdx.x >> 6;
    unsigned long long lmask_lt = (1ULL << lane) - 1ULL;
    float w1x = w1[lane*3+0], w1y = w1[lane*3+1], w1z = w1[lane*3+2], b1c = b1[lane];
    float s = 0.f, ss = 0.f;

    for (int t = 0; t < 8; ++t) {
      int i = nb*32 + wv*8 + t;        // query point (wave-uniform)
      float4 pi = pj[i];               // LDS broadcast
      unsigned u[16];
#pragma unroll
      for (int q = 0; q < 16; ++q) {
        int j = q*64 + lane;
        float4 pw = pj[j];
        float d = pi.w + pw.w - 2.0f*(pi.x*pw.x + pi.y*pw.y + pi.z*pw.z);
        unsigned bits = __float_as_uint(d);
        bits = (bits & 0x80000000u) ? ~bits : (bits | 0x80000000u);
        if (j == i) bits = 0xFFFFFFFFu;   // self excluded (diag = +inf)
        u[q] = bits;
      }
      // per-lane min of 16, then wave-min and wave-max-of-lane-mins via DPP
      unsigned lmin = u[0];
#pragma unroll
      for (int q = 1; q < 16; ++q) lmin = (u[q] < lmin) ? u[q] : lmin;
      unsigned rmin = lmin, rmax = lmin;
#define KNN_DPP_STEP(C) { \
      unsigned t1 = (unsigned)__builtin_amdgcn_update_dpp((int)rmin, (int)rmin, (C), 0xf, 0xf, false); \
      unsigned t2 = (unsigned)__builtin_amdgcn_update_dpp((int)rmax, (int)rmax, (C), 0xf, 0xf, false); \
      rmin = (t1 < rmin) ? t1 : rmin; rmax = (t2 > rmax) ? t2 : rmax; }
      KNN_DPP_STEP(0x111)   // row_shr:1
      KNN_DPP_STEP(0x112)   // row_shr:2
      KNN_DPP_STEP(0x114)   // row_shr:4
      KNN_DPP_STEP(0x118)   // row_shr:8
      KNN_DPP_STEP(0x142)   // row_bcast:15
      KNN_DPP_STEP(0x143)   // row_bcast:31
#undef KNN_DPP_STEP
      unsigned plo = ((unsigned)__builtin_amdgcn_readlane((int)rmin, 63)) >> 16;
      unsigned phi = ((unsigned)__builtin_amdgcn_readlane((int)rmax, 63)) >> 16;
      // narrowed binary search; carry the count measured at the final phi
      int cntHi = -1;
      while (plo < phi) {                 // wave-uniform
        unsigned pmid = (plo + phi) >> 1;
        unsigned tmid = (pmid << 16) | 0xFFFFu;
        int cnt = 0;
#pragma unroll
        for (int q = 0; q < 16; ++q)
          cnt += (int)__popcll(__ballot(u[q] <= tmid));
        if (cnt >= KNN) { phi = pmid; cntHi = cnt; } else plo = pmid + 1;
      }
      unsigned tstar = (phi << 16) | 0xFFFFu;  // bucket top
      unsigned bbase = phi << 16;              // bucket base
      int* op = idxg + (size_t)(b*NN + i) * KNN;
      if (cntHi < 0) {   // phi never measured (rare): recount
        cntHi = 0;
#pragma unroll
        for (int q = 0; q < 16; ++q)
          cntHi += (int)__popcll(__ballot(u[q] <= tstar));
      }
      if (cntHi == KNN) {
        // exact set: emit all <= tstar (index order; set-equivalent)
        int base = 0;
#pragma unroll
        for (int q = 0; q < 16; ++q) {
          bool pred = (u[q] <= tstar);
          unsigned long long mask = __ballot((int)pred);
          if (pred) {
            int p_ = base + (int)__popcll(mask & lmask_lt);
            op[p_] = q*64 + lane;
            nbrs[wv][p_] = q*64 + lane;
          }
          base += (int)__popcll(mask);
        }
      } else {
        // slow path: refine low 16 bits -> exact 20th value xstar
        unsigned lo2 = bbase, hi2 = tstar;
        while (lo2 < hi2) {
          unsigned mid = lo2 + ((hi2 - lo2) >> 1);
          int cnt = 0;
#pragma unroll
          for (int q = 0; q < 16; ++q)
            cnt += (int)__popcll(__ballot(u[q] <= mid));
          if (cnt >= KNN) hi2 = mid; else lo2 = mid + 1;
        }
        unsigned xstar = lo2;
        int base = 0;
#pragma unroll
        for (int q = 0; q < 16; ++q) {
          bool pred = (u[q] < xstar);
          unsigned long long mask = __ballot((int)pred);
          if (pred) {
            int p_ = base + (int)__popcll(mask & lmask_lt);
            op[p_] = q*64 + lane;
            nbrs[wv][p_] = q*64 + lane;
          }
          base += (int)__popcll(mask);
        }
        for (int q = 0; q < 16 && base < KNN; ++q) {  // ties, ascending index
          bool pred = (u[q] == xstar);
          unsigned long long mask = __ballot((int)pred);
          if (pred) {
            int p_ = base + (int)__popcll(mask & lmask_lt);
            if (p_ < KNN) { op[p_] = q*64 + lane; nbrs[wv][p_] = q*64 + lane; }
          }
          base += (int)__popcll(mask);
        }
      }
      // ---- BN1 stats epilogue for query i (lane = channel) ----
#pragma unroll 4
      for (int k = 0; k < KNN; ++k) {
        int j = nbrs[wv][k];           // wave-uniform broadcast
        float4 pw = pj[j];
        float h = fmaxf(fmaf(pw.x - pi.x, w1x,
                       fmaf(pw.y - pi.y, w1y,
                       fmaf(pw.z - pi.z, w1z, b1c))), 0.f);
        s += h; ss += h*h;
      }
    }
    // block reduce + atomics (channel = lane)
    red[wv][lane] = s; __syncthreads();
    if (wv == 0) atomicAdd(&acc1[lane], red[0][lane]+red[1][lane]+red[2][lane]+red[3][lane]);
    __syncthreads();
    red[wv][lane] = ss; __syncthreads();
    if (wv == 0) atomicAdd(&acc1[64+lane], red[0][lane]+red[1][lane]+red[2][lane]+red[3][lane]);
  } else {
    // ---------------- FPS phase 1 ----------------
    int b = blockIdx.x;
    float* base = (float*)pj;            // reuse 16 KB as 3 x NN floats
    float* sx = base; float* sy = base + NN; float* sz = base + 2*NN;
    const float* pb = pos + (size_t)b * NN * 3;
    for (int i = threadIdx.x; i < NN; i += 256) {
      sx[i] = pb[i*3+0]; sy[i] = pb[i*3+1]; sz[i] = pb[i*3+2];
    }
    __syncthreads();
    if (threadIdx.x >= 64) return;
    fps_phase(sx, sy, sz, fpsd, fpsc, fidxg, b, 1, FPS_R1);
  }
}

// ---------------- fold BN1 into w2 (bf16 B-fragment layout) ----------------
__global__ void fold1_kernel(const float* __restrict__ acc, const float* __restrict__ g1,
    const float* __restrict__ be1, const float* __restrict__ w2, const float* __restrict__ b2,
    unsigned short* __restrict__ w2bf, float* __restrict__ b2f) {
  __shared__ float s1[CC], t1[CC];
  int tid = threadIdx.x;  // 512 threads
  if (tid < CC) {
    float cnt = (float)CNT1;
    float m = acc[tid] / cnt;
    float v = acc[64+tid] / cnt - m*m;
    float sc = g1[tid] * rsqrtf(v + EPSF);
    s1[tid] = sc; t1[tid] = be1[tid] - m*sc;
  }
  __syncthreads();
  int frag = tid >> 6;        // 0..7  (nt = frag>>2, ks = frag&3)
  int lane = tid & 63;
  int nt = frag >> 2, ks = frag & 3;
  int cout = nt*32 + (lane & 31);
  int cin0 = ks*16 + (lane >> 5)*8;
  for (int j = 0; j < 8; ++j) {
    int cin = cin0 + j;
    w2bf[((size_t)frag*64 + lane)*8 + j] = f2bf(w2[cout*CC + cin] * s1[cin]);
  }
  if (tid < CC) {
    float accb = b2[tid];
    for (int ci = 0; ci < CC; ++ci) accb += t1[ci]*w2[tid*CC + ci];
    b2f[tid] = accb;
  }
}

// ---------------- conv2 via MFMA + FPS phase 2 (final) ----------------
__global__ __launch_bounds__(256, 4) void conv2_kernel(const float* __restrict__ pos,
    const int* __restrict__ idxg, const float* __restrict__ w1, const float* __restrict__ b1,
    const unsigned short* __restrict__ w2bf, const float* __restrict__ b2fg,
    float* __restrict__ maxh2, float* __restrict__ acc2,
    int* __restrict__ fidxg, float* __restrict__ fpsd, int* __restrict__ fpsc) {
  __shared__ float px[NN], py[NN], pz[NN];
  __shared__ float4 relw[4][KNN];
  __shared__ __align__(16) unsigned short h1s[4][2112];  // 8 groups * 264 ushorts
  __shared__ float redbuf[4][2*CC];
  if (blockIdx.x < BB) {
    // ---------------- FPS phase 2 (to completion) ----------------
    int b = blockIdx.x;
    const float* pb = pos + (size_t)b*NN*3;
    for (int i = threadIdx.x; i < NN; i += 256) {
      px[i] = pb[i*3+0]; py[i] = pb[i*3+1]; pz[i] = pb[i*3+2];
    }
    __syncthreads();
    if (threadIdx.x >= 64) return;
    fps_phase(px, py, pz, fpsd, fpsc, fidxg, b, FPS_R1, MM);
    return;
  }
  int blk = blockIdx.x - BB;
  int b = blk >> 4;
  int nb = blk & 15;
  const float* pb = pos + (size_t)b*NN*3;
  for (int i = threadIdx.x; i < NN; i += 256) {
    px[i] = pb[i*3+0]; py[i] = pb[i*3+1]; pz[i] = pb[i*3+2];
  }
  int lane = threadIdx.x & 63, w = threadIdx.x >> 6;
  int half = lane >> 5, l31 = lane & 31;
  short8 Bf[2][4];
#pragma unroll
  for (int nt = 0; nt < 2; ++nt)
#pragma unroll
    for (int ks = 0; ks < 4; ++ks)
      Bf[nt][ks] = *(const short8*)&w2bf[((size_t)(nt*4+ks)*64 + lane)*8];
  float b2o0 = b2fg[l31], b2o1 = b2fg[32 + l31];
  float w1x = w1[lane*3+0], w1y = w1[lane*3+1], w1z = w1[lane*3+2], b1c = b1[lane];
  unsigned short* hw = h1s[w];
  {
    short8 zz = {0,0,0,0,0,0,0,0};
    for (int z = lane; z < 96; z += 64) {
      int g = z / 12, r = 20 + z % 12;
      *(short8*)&hw[g*264 + r*8] = zz;
    }
  }
  float sA = 0.f, ssA = 0.f, sB = 0.f, ssB = 0.f;
  __syncthreads();
  for (int t = 0; t < 16; ++t) {
    int n = nb*64 + w*16 + t;
    if (lane < KNN) {
      int j = idxg[(size_t)(b*NN + n)*KNN + lane];
      relw[w][lane] = make_float4(px[j]-px[n], py[j]-py[n], pz[j]-pz[n], 0.f);
    }
    int gbase = (lane >> 3)*264 + (lane & 7);
#pragma unroll
    for (int k = 0; k < KNN; ++k) {
      float4 r4 = relw[w][k];   // wave-uniform broadcast read
      float h = fmaxf(fmaf(r4.x, w1x, fmaf(r4.y, w1y, fmaf(r4.z, w1z, b1c))), 0.f);
      hw[gbase + k*8] = f2bf(h);
    }
    f32x16 acc0 = {}; f32x16 acc1 = {};
#pragma unroll
    for (int ks = 0; ks < 4; ++ks) {
      short8 A = *(const short8*)&hw[(ks*2 + half)*264 + l31*8];
      acc0 = __builtin_amdgcn_mfma_f32_32x32x16_bf16(A, Bf[0][ks], acc0, 0, 0, 0);
      acc1 = __builtin_amdgcn_mfma_f32_32x32x16_bf16(A, Bf[1][ks], acc1, 0, 0, 0);
    }
    float mx0 = 0.f, mx1 = 0.f;
#pragma unroll
    for (int reg = 0; reg < 8; ++reg) {
      float v0 = fmaxf(acc0[reg] + b2o0, 0.f);
      float v1 = fmaxf(acc1[reg] + b2o1, 0.f);
      sA += v0; ssA += v0*v0; sB += v1; ssB += v1*v1;
      mx0 = fmaxf(mx0, v0); mx1 = fmaxf(mx1, v1);
    }
    if (half == 0) {
#pragma unroll
      for (int reg = 8; reg < 12; ++reg) {
        float v0 = fmaxf(acc0[reg] + b2o0, 0.f);
        float v1 = fmaxf(acc1[reg] + b2o1, 0.f);
        sA += v0; ssA += v0*v0; sB += v1; ssB += v1*v1;
        mx0 = fmaxf(mx0, v0); mx1 = fmaxf(mx1, v1);
      }
    }
    mx0 = fmaxf(mx0, __shfl_xor(mx0, 32, 64));
    mx1 = fmaxf(mx1, __shfl_xor(mx1, 32, 64));
    if (half == 0) {
      float* mp = maxh2 + (size_t)(b*NN + n)*CC;
      mp[l31] = mx0; mp[32 + l31] = mx1;
    }
  }
  sA += __shfl_xor(sA, 32, 64); ssA += __shfl_xor(ssA, 32, 64);
  sB += __shfl_xor(sB, 32, 64); ssB += __shfl_xor(ssB, 32, 64);
  if (half == 0) { redbuf[w][l31] = sA; redbuf[w][32 + l31] = sB; }
  __syncthreads();
  if (w == 0) atomicAdd(&acc2[lane], redbuf[0][lane]+redbuf[1][lane]+redbuf[2][lane]+redbuf[3][lane]);
  __syncthreads();
  if (half == 0) { redbuf[w][l31] = ssA; redbuf[w][32 + l31] = ssB; }
  __syncthreads();
  if (w == 0) atomicAdd(&acc2[64+lane], redbuf[0][lane]+redbuf[1][lane]+redbuf[2][lane]+redbuf[3][lane]);
}

// ---------------- head: Y[b,h] = relu(max_m(f@w_nn1^T)+b) ----------------
// fold2 fused: s2/t2 computed per block from acc2 (bit-identical arithmetic).
// 2 h-channels per thread (h, h+64): halves ds_read_b128 traffic per FLOP.
__global__ __launch_bounds__(256) void head_kernel(const float* __restrict__ maxh2,
    const int* __restrict__ fidxg, const float* __restrict__ acc2,
    const float* __restrict__ g2, const float* __restrict__ be2,
    const float* __restrict__ wnn1, const float* __restrict__ bnn1, float* __restrict__ Y) {
  int b = blockIdx.x >> 2;
  int hc = blockIdx.x & 3;
  __shared__ __align__(16) float ftile[128][CC];
  __shared__ float red2[4][128];
  __shared__ float s2s[CC], t2s[CC];
  if (threadIdx.x < CC) {
    int c = threadIdx.x;
    float cnt = (float)CNT1;
    float m = acc2[c]/cnt;
    float v = acc2[64+c]/cnt - m*m;
    float sc = g2[c]*rsqrtf(v+EPSF);
    s2s[c] = sc;
    t2s[c] = be2[c] - m*sc;
  }
  int hl = threadIdx.x & 63, mseg = threadIdx.x >> 6;   // 64 h-lanes x 4 msegs
  int hA = hc*128 + hl, hB = hA + 64;
  float4 wva[16], wvb[16];
  const float4* wrA = (const float4*)(wnn1 + (size_t)hA*CC);
  const float4* wrB = (const float4*)(wnn1 + (size_t)hB*CC);
#pragma unroll
  for (int q = 0; q < 16; ++q) { wva[q] = wrA[q]; wvb[q] = wrB[q]; }
  float bestA = -FLT_MAX, bestB = -FLT_MAX;
  const int* fb = fidxg + b*MM;
  __syncthreads();
  for (int chunk = 0; chunk < 2; ++chunk) {
    {
      int row = threadIdx.x & 127, chal = threadIdx.x >> 7;
      int fi = fb[chunk*128 + row];
      const float* src = maxh2 + (size_t)(b*NN + fi)*CC;
      for (int ci = chal*32; ci < chal*32+32; ++ci)
        ftile[row][ci] = s2s[ci]*src[ci] + t2s[ci];
    }
    __syncthreads();
    for (int m = mseg*32; m < mseg*32+32; ++m) {
      float accA = 0.f, accB = 0.f;
#pragma unroll
      for (int cq = 0; cq < 16; ++cq) {
        float4 f = *((const float4*)&ftile[m][cq*4]);
        accA = fmaf(f.x, wva[cq].x, accA);
        accA = fmaf(f.y, wva[cq].y, accA);
        accA = fmaf(f.z, wva[cq].z, accA);
        accA = fmaf(f.w, wva[cq].w, accA);
        accB = fmaf(f.x, wvb[cq].x, accB);
        accB = fmaf(f.y, wvb[cq].y, accB);
        accB = fmaf(f.z, wvb[cq].z, accB);
        accB = fmaf(f.w, wvb[cq].w, accB);
      }
      bestA = fmaxf(bestA, accA);
      bestB = fmaxf(bestB, accB);
    }
    __syncthreads();
  }
  red2[mseg][hl] = bestA;
  red2[mseg][64 + hl] = bestB;
  __syncthreads();
  if (threadIdx.x < 128) {
    int hh = hc*128 + threadIdx.x;
    float v = fmaxf(fmaxf(red2[0][threadIdx.x], red2[1][threadIdx.x]),
                    fmaxf(red2[2][threadIdx.x], red2[3][threadIdx.x])) + bnn1[hh];
    Y[(size_t)b*HH + hh] = fmaxf(v, 0.f);
  }
}

// ---------------- logits + log_softmax (bn3 fused per block) ----------------
__global__ __launch_bounds__(256) void logits_kernel(const float* __restrict__ Y,
    const float* __restrict__ g3, const float* __restrict__ be3,
    const float* __restrict__ w4, const float* __restrict__ b4, float* __restrict__ out) {
  int b = blockIdx.x;
  __shared__ float ybn[HH];
  __shared__ float s3s[HH], t3s[HH];
  __shared__ float lg[NCLS];
  __shared__ float lse;
  // bn3 recomputed per block (bit-identical ordering)
  for (int h = threadIdx.x; h < HH; h += 256) {
    float s = 0.f;
    for (int bb = 0; bb < BB; ++bb) s += Y[(size_t)bb*HH + h];
    float m = s / (float)BB;
    float v = 0.f;
    for (int bb = 0; bb < BB; ++bb) { float d = Y[(size_t)bb*HH + h] - m; v += d*d; }
    v /= (float)BB;
    float sc = g3[h] * rsqrtf(v + EPSF);
    s3s[h] = sc; t3s[h] = be3[h] - m*sc;
  }
  __syncthreads();
  for (int hh = threadIdx.x; hh < HH; hh += 256)
    ybn[hh] = Y[(size_t)b*HH + hh]*s3s[hh] + t3s[hh];
  __syncthreads();
  if (threadIdx.x < NCLS) {
    int j = threadIdx.x;
    float acc = b4[j];
    const float* wr = w4 + (size_t)j*HH;
    for (int ci = 0; ci < HH; ++ci) acc = fmaf(ybn[ci], wr[ci], acc);
    lg[j] = acc;
  }
  __syncthreads();
  if (threadIdx.x == 0) {
    float mx = -FLT_MAX;
    for (int j = 0; j < NCLS; ++j) mx = fmaxf(mx, lg[j]);
    float s = 0.f;
    for (int j = 0; j < NCLS; ++j) s += expf(lg[j] - mx);
    lse = mx + logf(s);
  }
  __syncthreads();
  if (threadIdx.x < NCLS) out[b*NCLS + threadIdx.x] = lg[threadIdx.x] - lse;
}

extern "C" void kernel_launch(void* const* d_in, const int* in_sizes, int n_in,
                              void* d_out, int out_size, void* d_ws, size_t ws_size,
                              hipStream_t stream) {
  const float* pos  = (const float*)d_in[0];
  const float* w1   = (const float*)d_in[1];
  const float* b1   = (const float*)d_in[2];
  const float* g1   = (const float*)d_in[3];
  const float* be1  = (const float*)d_in[4];
  const float* w2   = (const float*)d_in[5];
  const float* b2   = (const float*)d_in[6];
  const float* g2   = (const float*)d_in[7];
  const float* be2  = (const float*)d_in[8];
  const float* wnn1 = (const float*)d_in[9];
  const float* bnn1 = (const float*)d_in[10];
  const float* gbn2 = (const float*)d_in[11];
  const float* bebn2= (const float*)d_in[12];
  const float* wnn4 = (const float*)d_in[13];
  const float* bnn4 = (const float*)d_in[14];
  float* ws = (float*)d_ws;
  int*   idxg  = (int*)(ws + IDX_OFF);
  float* maxh2 = ws + MAXH2_OFF;
  int*   fidxg = (int*)(ws + FIDX_OFF);
  float* Y     = ws + Y_OFF;
  float* acc1  = ws + ACC_OFF;
  float* acc2  = ws + ACC_OFF + 128;
  unsigned short* w2bf = (unsigned short*)(ws + W2T_OFF);
  float* b2f   = ws + B2F_OFF;
  float* fpsd  = ws + FPSD_OFF;
  int*   fpsc  = (int*)(ws + FPSC_OFF);
  float* outp  = (float*)d_out;

  hipMemsetAsync((void*)(ws + ACC_OFF), 0, 256*sizeof(float), stream);
  knn_fps_kernel<<<BB + BB*32, 256, 0, stream>>>(pos, idxg, fidxg, fpsd, fpsc, w1, b1, acc1);
  fold1_kernel<<<1, 512, 0, stream>>>(acc1, g1, be1, w2, b2, w2bf, b2f);
  conv2_kernel<<<BB + BB*16, 256, 0, stream>>>(pos, idxg, w1, b1, w2bf, b2f, maxh2, acc2, fidxg, fpsd, fpsc);
  head_kernel<<<BB*4, 256, 0, stream>>>(maxh2, fidxg, acc2, g2, be2, wnn1, bnn1, Y);
  logits_kernel<<<BB, 256, 0, stream>>>(Y, gbn2, bebn2, wnn4, bnn4, outp);
}

// Round 13
// 335.763 us; speedup vs baseline: 1.2186x; 1.0014x over previous
//
#include <hip/hip_runtime.h>
#include <hip/hip_bf16.h>
#include <cfloat>
#include <math.h>

#define BB 64
#define NN 1024
#define KNN 20
#define MM 256
#define CC 64
#define HH 512
#define NCLS 40
#define EPSF 1e-5f
#define CNT1 (BB*NN*KNN)

// FPS phase boundaries: phase1 rounds [1,FPS_R1) under K1 (knn+stats),
// phase2 [FPS_R1,MM) under conv2.
#define FPS_R1 201

// workspace offsets (in 4-byte elements)
#define IDX_OFF    0
#define MAXH2_OFF  (IDX_OFF + BB*NN*KNN)      // int idx then floats
#define FIDX_OFF   (MAXH2_OFF + BB*NN*CC)
#define Y_OFF      (FIDX_OFF + BB*MM)
#define ACC_OFF    (Y_OFF + BB*HH)            // 256 floats zeroed: sum1[64],sumsq1[64],sum2[64],sumsq2[64]
#define W2T_OFF    (ACC_OFF + 256)            // w2' bf16 B-frags (2048 ushorts) + b2f
#define B2F_OFF    (W2T_OFF + CC*CC)
#define FPSD_OFF   (B2F_OFF + CC)             // BB*NN floats: FPS dist state
#define FPSC_OFF   (FPSD_OFF + BB*NN)         // BB ints: FPS cur state

typedef __attribute__((ext_vector_type(8)))  short short8;
typedef __attribute__((ext_vector_type(16))) float f32x16;

static __device__ __forceinline__ unsigned short f2bf(float f) {
  unsigned u = __float_as_uint(f);
  unsigned r = (u + 0x7fffu + ((u >> 16) & 1u)) >> 16;   // RNE
  return (unsigned short)r;
}

// orderable encode/decode: float total order <-> unsigned total order
static __device__ __forceinline__ unsigned fenc(float f) {
  unsigned b = __float_as_uint(f);
  return b ^ ((unsigned)((int)b >> 31) | 0x80000000u);
}
static __device__ __forceinline__ float fdec(unsigned e) {
  return __uint_as_float((e & 0x80000000u) ? (e & 0x7FFFFFFFu) : ~e);
}

// popcount(mask & ((1<<lane)-1)) via native mbcnt pair
static __device__ __forceinline__ int mbcnt64(unsigned long long m) {
  return (int)__builtin_amdgcn_mbcnt_hi((unsigned)(m >> 32),
           __builtin_amdgcn_mbcnt_lo((unsigned)m, 0));
}

// ---------------- FPS phase (single wave; caller: threadIdx.x < 64) ----------------
// All-float reduction (dist >= +0 so fmaxf == bit-max, float eq == bit eq);
// bit-exact vs numpy (max dist, ties -> smallest index). State checkpointed
// to global between phases.
static __device__ __forceinline__ void fps_phase(
    const float* sx, const float* sy, const float* sz,   // LDS, NN each
    float* fpsd, int* fpsc, int* fidxg, int b, int mStart, int mEnd) {
  int lane = threadIdx.x;
  float lx[16], ly[16], lz[16], dist[16];
#pragma unroll
  for (int q = 0; q < 16; ++q) {
    int j = q*64 + lane;
    lx[q] = sx[j]; ly[q] = sy[j]; lz[q] = sz[j];
  }
  int cur;
  if (mStart <= 1) {
#pragma unroll
    for (int q = 0; q < 16; ++q) dist[q] = 1e38f;
    if (lane == 0) fidxg[b*MM] = 0;
    cur = 0;
  } else {
#pragma unroll
    for (int q = 0; q < 16; ++q) dist[q] = fpsd[b*NN + q*64 + lane];
    cur = fpsc[b];
  }
  for (int m = mStart; m < mEnd; ++m) {
    float cpx = sx[cur], cpy = sy[cur], cpz = sz[cur];   // uniform LDS broadcast
#pragma unroll
    for (int q = 0; q < 16; ++q) {
      float dx = __fsub_rn(lx[q], cpx);
      float dy = __fsub_rn(ly[q], cpy);
      float dz = __fsub_rn(lz[q], cpz);
      float dd = __fadd_rn(__fadd_rn(__fmul_rn(dx,dx), __fmul_rn(dy,dy)), __fmul_rn(dz,dz));
      dist[q] = fminf(dist[q], dd);
    }
    float t8[8];
#pragma unroll
    for (int q = 0; q < 8; ++q) t8[q] = fmaxf(dist[q], dist[q + 8]);
#pragma unroll
    for (int q = 0; q < 4; ++q) t8[q] = fmaxf(t8[q], t8[q + 4]);
    float r = fmaxf(fmaxf(t8[0], t8[1]), fmaxf(t8[2], t8[3]));
#define FPS_VMAX_STEP(C) { \
    int tt = __builtin_amdgcn_update_dpp(__float_as_int(r), __float_as_int(r), (C), 0xf, 0xf, false); \
    r = fmaxf(r, __int_as_float(tt)); }
    FPS_VMAX_STEP(0x111)   // row_shr:1
    FPS_VMAX_STEP(0x112)   // row_shr:2
    FPS_VMAX_STEP(0x114)   // row_shr:4
    FPS_VMAX_STEP(0x118)   // row_shr:8
    FPS_VMAX_STEP(0x142)   // row_bcast:15
    FPS_VMAX_STEP(0x143)   // row_bcast:31
#undef FPS_VMAX_STEP
    float wmax = __int_as_float(__builtin_amdgcn_readlane(__float_as_int(r), 63));
    unsigned ci = 0xFFFFFFFFu;
#pragma unroll
    for (int q = 15; q >= 0; --q)
      if (dist[q] == wmax) ci = (unsigned)(q*64 + lane);
#define FPS_IMIN_STEP(C) { \
    unsigned tt = (unsigned)__builtin_amdgcn_update_dpp((int)ci, (int)ci, (C), 0xf, 0xf, false); \
    ci = (tt < ci) ? tt : ci; }
    FPS_IMIN_STEP(0x111)
    FPS_IMIN_STEP(0x112)
    FPS_IMIN_STEP(0x114)
    FPS_IMIN_STEP(0x118)
    FPS_IMIN_STEP(0x142)
    FPS_IMIN_STEP(0x143)
#undef FPS_IMIN_STEP
    cur = (int)(unsigned)__builtin_amdgcn_readlane((int)ci, 63);
    if (lane == 0) fidxg[b*MM + m] = cur;
  }
  if (mEnd < MM) {   // checkpoint
#pragma unroll
    for (int q = 0; q < 16; ++q) fpsd[b*NN + q*64 + lane] = dist[q];
    if (lane == 0) fpsc[b] = cur;
  }
}

// ---------------- fused FPS(phase1) + kNN + BN1 stats ----------------
// blocks [0, BB): FPS rounds [1, FPS_R1).
// blocks [BB, BB + BB*32): kNN in FLOAT domain: distances stay float;
// binary search midpoints are decoded (scalar) to float thresholds for
// v_cmp_le_f32 — no per-candidate orderable encode. Value-space ordering
// == encoded ordering (bit-exact same sets as R8-R12). BN1-stats epilogue
// fused (lane=channel), indices mirrored via per-wave LDS.
__global__ __launch_bounds__(256) void knn_fps_kernel(const float* __restrict__ pos,
                                                      int* __restrict__ idxg,
                                                      int* __restrict__ fidxg,
                                                      float* __restrict__ fpsd,
                                                      int* __restrict__ fpsc,
                                                      const float* __restrict__ w1,
                                                      const float* __restrict__ b1,
                                                      float* __restrict__ acc1) {
  __shared__ float4 pj[NN];
  __shared__ int nbrs[4][KNN];
  __shared__ float red[4][CC];
  if (blockIdx.x >= BB) {
    // ---------------- kNN + stats branch ----------------
    int blk = blockIdx.x - BB;
    int b  = blk >> 5;   // cloud
    int nb = blk & 31;   // 32-point segment of the cloud
    const float* pb = pos + (size_t)b * NN * 3;
    for (int i = threadIdx.x; i < NN; i += 256) {
      float x = pb[i*3+0], y = pb[i*3+1], z = pb[i*3+2];
      pj[i] = make_float4(x, y, z, (x*x + y*y) + z*z);
    }
    __syncthreads();
    int lane = threadIdx.x & 63;
    int wv   = threadIdx.x >> 6;
    float w1x = w1[lane*3+0], w1y = w1[lane*3+1], w1z = w1[lane*3+2], b1c = b1[lane];
    float s = 0.f, ss = 0.f;

    for (int t = 0; t < 8; ++t) {
      int i = nb*32 + wv*8 + t;        // query point (wave-uniform)
      float4 pi = pj[i];               // LDS broadcast
      float dq[16];
#pragma unroll
      for (int q = 0; q < 16; ++q) {
        int j = q*64 + lane;
        float4 pw = pj[j];
        float d = pi.w + pw.w - 2.0f*(pi.x*pw.x + pi.y*pw.y + pi.z*pw.z);
        if (j == i) d = FLT_MAX;       // self excluded
        dq[q] = d;
      }
      // per-lane min of 16, then wave-min and wave-max-of-lane-mins via DPP
      float lmin = dq[0];
#pragma unroll
      for (int q = 1; q < 16; ++q) lmin = fminf(lmin, dq[q]);
      float rmin = lmin, rmax = lmin;
#define KNN_DPP_STEP(C) { \
      int t1 = __builtin_amdgcn_update_dpp(__float_as_int(rmin), __float_as_int(rmin), (C), 0xf, 0xf, false); \
      int t2 = __builtin_amdgcn_update_dpp(__float_as_int(rmax), __float_as_int(rmax), (C), 0xf, 0xf, false); \
      rmin = fminf(rmin, __int_as_float(t1)); rmax = fmaxf(rmax, __int_as_float(t2)); }
      KNN_DPP_STEP(0x111)   // row_shr:1
      KNN_DPP_STEP(0x112)   // row_shr:2
      KNN_DPP_STEP(0x114)   // row_shr:4
      KNN_DPP_STEP(0x118)   // row_shr:8
      KNN_DPP_STEP(0x142)   // row_bcast:15
      KNN_DPP_STEP(0x143)   // row_bcast:31
#undef KNN_DPP_STEP
      unsigned eminv = fenc(rmin), emaxv = fenc(rmax);
      unsigned plo = ((unsigned)__builtin_amdgcn_readlane((int)eminv, 63)) >> 16;
      unsigned phi = ((unsigned)__builtin_amdgcn_readlane((int)emaxv, 63)) >> 16;
      // narrowed binary search in float space; carry count at final phi
      int cntHi = -1;
      while (plo < phi) {                 // wave-uniform
        unsigned pmid = (plo + phi) >> 1;
        float tf = fdec((pmid << 16) | 0xFFFFu);
        int cnt = 0;
#pragma unroll
        for (int q = 0; q < 16; ++q)
          cnt += (int)__popcll(__ballot(dq[q] <= tf));
        if (cnt >= KNN) { phi = pmid; cntHi = cnt; } else plo = pmid + 1;
      }
      float tsf = fdec((phi << 16) | 0xFFFFu);   // bucket-top value
      int* op = idxg + (size_t)(b*NN + i) * KNN;
      if (cntHi < 0) {   // phi never measured (rare): recount
        cntHi = 0;
#pragma unroll
        for (int q = 0; q < 16; ++q)
          cntHi += (int)__popcll(__ballot(dq[q] <= tsf));
      }
      if (cntHi == KNN) {
        // exact set: emit all <= tsf (index order; set-equivalent)
        int base = 0;
#pragma unroll
        for (int q = 0; q < 16; ++q) {
          bool pred = (dq[q] <= tsf);
          unsigned long long mask = __ballot((int)pred);
          if (pred) {
            int p_ = base + mbcnt64(mask);
            op[p_] = q*64 + lane;
            nbrs[wv][p_] = q*64 + lane;
          }
          base += (int)__popcll(mask);
        }
      } else {
        // slow path: refine low 16 bits -> exact 20th value
        unsigned lo2 = phi << 16, hi2 = (phi << 16) | 0xFFFFu;
        while (lo2 < hi2) {
          unsigned mid = lo2 + ((hi2 - lo2) >> 1);
          float mf = fdec(mid);
          int cnt = 0;
#pragma unroll
          for (int q = 0; q < 16; ++q)
            cnt += (int)__popcll(__ballot(dq[q] <= mf));
          if (cnt >= KNN) hi2 = mid; else lo2 = mid + 1;
        }
        float xsf = fdec(lo2);
        int base = 0;
#pragma unroll
        for (int q = 0; q < 16; ++q) {
          bool pred = (dq[q] < xsf);
          unsigned long long mask = __ballot((int)pred);
          if (pred) {
            int p_ = base + mbcnt64(mask);
            op[p_] = q*64 + lane;
            nbrs[wv][p_] = q*64 + lane;
          }
          base += (int)__popcll(mask);
        }
        for (int q = 0; q < 16 && base < KNN; ++q) {  // ties, ascending index
          bool pred = (dq[q] == xsf);
          unsigned long long mask = __ballot((int)pred);
          if (pred) {
            int p_ = base + mbcnt64(mask);
            if (p_ < KNN) { op[p_] = q*64 + lane; nbrs[wv][p_] = q*64 + lane; }
          }
          base += (int)__popcll(mask);
        }
      }
      // ---- BN1 stats epilogue for query i (lane = channel) ----
#pragma unroll 4
      for (int k = 0; k < KNN; ++k) {
        int j = nbrs[wv][k];           // wave-uniform broadcast
        float4 pw = pj[j];
        float h = fmaxf(fmaf(pw.x - pi.x, w1x,
                       fmaf(pw.y - pi.y, w1y,
                       fmaf(pw.z - pi.z, w1z, b1c))), 0.f);
        s += h; ss += h*h;
      }
    }
    // block reduce + atomics (channel = lane)
    red[wv][lane] = s; __syncthreads();
    if (wv == 0) atomicAdd(&acc1[lane], red[0][lane]+red[1][lane]+red[2][lane]+red[3][lane]);
    __syncthreads();
    red[wv][lane] = ss; __syncthreads();
    if (wv == 0) atomicAdd(&acc1[64+lane], red[0][lane]+red[1][lane]+red[2][lane]+red[3][lane]);
  } else {
    // ---------------- FPS phase 1 ----------------
    int b = blockIdx.x;
    float* base = (float*)pj;            // reuse 16 KB as 3 x NN floats
    float* sx = base; float* sy = base + NN; float* sz = base + 2*NN;
    const float* pb = pos + (size_t)b * NN * 3;
    for (int i = threadIdx.x; i < NN; i += 256) {
      sx[i] = pb[i*3+0]; sy[i] = pb[i*3+1]; sz[i] = pb[i*3+2];
    }
    __syncthreads();
    if (threadIdx.x >= 64) return;
    fps_phase(sx, sy, sz, fpsd, fpsc, fidxg, b, 1, FPS_R1);
  }
}

// ---------------- fold BN1 into w2 (bf16 B-fragment layout) ----------------
__global__ void fold1_kernel(const float* __restrict__ acc, const float* __restrict__ g1,
    const float* __restrict__ be1, const float* __restrict__ w2, const float* __restrict__ b2,
    unsigned short* __restrict__ w2bf, float* __restrict__ b2f) {
  __shared__ float s1[CC], t1[CC];
  int tid = threadIdx.x;  // 512 threads
  if (tid < CC) {
    float cnt = (float)CNT1;
    float m = acc[tid] / cnt;
    float v = acc[64+tid] / cnt - m*m;
    float sc = g1[tid] * rsqrtf(v + EPSF);
    s1[tid] = sc; t1[tid] = be1[tid] - m*sc;
  }
  __syncthreads();
  int frag = tid >> 6;        // 0..7  (nt = frag>>2, ks = frag&3)
  int lane = tid & 63;
  int nt = frag >> 2, ks = frag & 3;
  int cout = nt*32 + (lane & 31);
  int cin0 = ks*16 + (lane >> 5)*8;
  for (int j = 0; j < 8; ++j) {
    int cin = cin0 + j;
    w2bf[((size_t)frag*64 + lane)*8 + j] = f2bf(w2[cout*CC + cin] * s1[cin]);
  }
  if (tid < CC) {
    float accb = b2[tid];
    for (int ci = 0; ci < CC; ++ci) accb += t1[ci]*w2[tid*CC + ci];
    b2f[tid] = accb;
  }
}

// ---------------- conv2 via MFMA + FPS phase 2 (final) ----------------
// idxg gather software-prefetched one iteration ahead: the (likely cross-XCD
// L2-miss) load latency hides under the current iteration's MFMA/epilogue.
__global__ __launch_bounds__(256, 4) void conv2_kernel(const float* __restrict__ pos,
    const int* __restrict__ idxg, const float* __restrict__ w1, const float* __restrict__ b1,
    const unsigned short* __restrict__ w2bf, const float* __restrict__ b2fg,
    float* __restrict__ maxh2, float* __restrict__ acc2,
    int* __restrict__ fidxg, float* __restrict__ fpsd, int* __restrict__ fpsc) {
  __shared__ float px[NN], py[NN], pz[NN];
  __shared__ float4 relw[4][KNN];
  __shared__ __align__(16) unsigned short h1s[4][2112];  // 8 groups * 264 ushorts
  __shared__ float redbuf[4][2*CC];
  if (blockIdx.x < BB) {
    // ---------------- FPS phase 2 (to completion) ----------------
    int b = blockIdx.x;
    const float* pb = pos + (size_t)b*NN*3;
    for (int i = threadIdx.x; i < NN; i += 256) {
      px[i] = pb[i*3+0]; py[i] = pb[i*3+1]; pz[i] = pb[i*3+2];
    }
    __syncthreads();
    if (threadIdx.x >= 64) return;
    fps_phase(px, py, pz, fpsd, fpsc, fidxg, b, FPS_R1, MM);
    return;
  }
  int blk = blockIdx.x - BB;
  int b = blk >> 4;
  int nb = blk & 15;
  const float* pb = pos + (size_t)b*NN*3;
  for (int i = threadIdx.x; i < NN; i += 256) {
    px[i] = pb[i*3+0]; py[i] = pb[i*3+1]; pz[i] = pb[i*3+2];
  }
  int lane = threadIdx.x & 63, w = threadIdx.x >> 6;
  int half = lane >> 5, l31 = lane & 31;
  short8 Bf[2][4];
#pragma unroll
  for (int nt = 0; nt < 2; ++nt)
#pragma unroll
    for (int ks = 0; ks < 4; ++ks)
      Bf[nt][ks] = *(const short8*)&w2bf[((size_t)(nt*4+ks)*64 + lane)*8];
  float b2o0 = b2fg[l31], b2o1 = b2fg[32 + l31];
  float w1x = w1[lane*3+0], w1y = w1[lane*3+1], w1z = w1[lane*3+2], b1c = b1[lane];
  unsigned short* hw = h1s[w];
  {
    short8 zz = {0,0,0,0,0,0,0,0};
    for (int z = lane; z < 96; z += 64) {
      int g = z / 12, r = 20 + z % 12;
      *(short8*)&hw[g*264 + r*8] = zz;
    }
  }
  float sA = 0.f, ssA = 0.f, sB = 0.f, ssB = 0.f;
  int nxt = 0;
  {
    int n0 = nb*64 + w*16;
    if (lane < KNN) nxt = idxg[(size_t)(b*NN + n0)*KNN + lane];
  }
  __syncthreads();
  for (int t = 0; t < 16; ++t) {
    int n = nb*64 + w*16 + t;
    if (lane < KNN) {
      int j = nxt;
      relw[w][lane] = make_float4(px[j]-px[n], py[j]-py[n], pz[j]-pz[n], 0.f);
      if (t < 15) nxt = idxg[(size_t)(b*NN + n + 1)*KNN + lane];  // prefetch
    }
    int gbase = (lane >> 3)*264 + (lane & 7);
#pragma unroll
    for (int k = 0; k < KNN; ++k) {
      float4 r4 = relw[w][k];   // wave-uniform broadcast read
      float h = fmaxf(fmaf(r4.x, w1x, fmaf(r4.y, w1y, fmaf(r4.z, w1z, b1c))), 0.f);
      hw[gbase + k*8] = f2bf(h);
    }
    f32x16 acc0 = {}; f32x16 acc1 = {};
#pragma unroll
    for (int ks = 0; ks < 4; ++ks) {
      short8 A = *(const short8*)&hw[(ks*2 + half)*264 + l31*8];
      acc0 = __builtin_amdgcn_mfma_f32_32x32x16_bf16(A, Bf[0][ks], acc0, 0, 0, 0);
      acc1 = __builtin_amdgcn_mfma_f32_32x32x16_bf16(A, Bf[1][ks], acc1, 0, 0, 0);
    }
    float mx0 = 0.f, mx1 = 0.f;
#pragma unroll
    for (int reg = 0; reg < 8; ++reg) {
      float v0 = fmaxf(acc0[reg] + b2o0, 0.f);
      float v1 = fmaxf(acc1[reg] + b2o1, 0.f);
      sA += v0; ssA += v0*v0; sB += v1; ssB += v1*v1;
      mx0 = fmaxf(mx0, v0); mx1 = fmaxf(mx1, v1);
    }
    if (half == 0) {
#pragma unroll
      for (int reg = 8; reg < 12; ++reg) {
        float v0 = fmaxf(acc0[reg] + b2o0, 0.f);
        float v1 = fmaxf(acc1[reg] + b2o1, 0.f);
        sA += v0; ssA += v0*v0; sB += v1; ssB += v1*v1;
        mx0 = fmaxf(mx0, v0); mx1 = fmaxf(mx1, v1);
      }
    }
    mx0 = fmaxf(mx0, __shfl_xor(mx0, 32, 64));
    mx1 = fmaxf(mx1, __shfl_xor(mx1, 32, 64));
    if (half == 0) {
      float* mp = maxh2 + (size_t)(b*NN + n)*CC;
      mp[l31] = mx0; mp[32 + l31] = mx1;
    }
  }
  sA += __shfl_xor(sA, 32, 64); ssA += __shfl_xor(ssA, 32, 64);
  sB += __shfl_xor(sB, 32, 64); ssB += __shfl_xor(ssB, 32, 64);
  if (half == 0) { redbuf[w][l31] = sA; redbuf[w][32 + l31] = sB; }
  __syncthreads();
  if (w == 0) atomicAdd(&acc2[lane], redbuf[0][lane]+redbuf[1][lane]+redbuf[2][lane]+redbuf[3][lane]);
  __syncthreads();
  if (half == 0) { redbuf[w][l31] = ssA; redbuf[w][32 + l31] = ssB; }
  __syncthreads();
  if (w == 0) atomicAdd(&acc2[64+lane], redbuf[0][lane]+redbuf[1][lane]+redbuf[2][lane]+redbuf[3][lane]);
}

// ---------------- head: Y[b,h] = relu(max_m(f@w_nn1^T)+b) ----------------
// fold2 fused: s2/t2 computed per block from acc2 (bit-identical arithmetic).
// 2 h-channels per thread (h, h+64): halves ds_read_b128 traffic per FLOP.
__global__ __launch_bounds__(256) void head_kernel(const float* __restrict__ maxh2,
    const int* __restrict__ fidxg, const float* __restrict__ acc2,
    const float* __restrict__ g2, const float* __restrict__ be2,
    const float* __restrict__ wnn1, const float* __restrict__ bnn1, float* __restrict__ Y) {
  int b = blockIdx.x >> 2;
  int hc = blockIdx.x & 3;
  __shared__ __align__(16) float ftile[128][CC];
  __shared__ float red2[4][128];
  __shared__ float s2s[CC], t2s[CC];
  if (threadIdx.x < CC) {
    int c = threadIdx.x;
    float cnt = (float)CNT1;
    float m = acc2[c]/cnt;
    float v = acc2[64+c]/cnt - m*m;
    float sc = g2[c]*rsqrtf(v+EPSF);
    s2s[c] = sc;
    t2s[c] = be2[c] - m*sc;
  }
  int hl = threadIdx.x & 63, mseg = threadIdx.x >> 6;   // 64 h-lanes x 4 msegs
  int hA = hc*128 + hl, hB = hA + 64;
  float4 wva[16], wvb[16];
  const float4* wrA = (const float4*)(wnn1 + (size_t)hA*CC);
  const float4* wrB = (const float4*)(wnn1 + (size_t)hB*CC);
#pragma unroll
  for (int q = 0; q < 16; ++q) { wva[q] = wrA[q]; wvb[q] = wrB[q]; }
  float bestA = -FLT_MAX, bestB = -FLT_MAX;
  const int* fb = fidxg + b*MM;
  __syncthreads();
  for (int chunk = 0; chunk < 2; ++chunk) {
    {
      int row = threadIdx.x & 127, chal = threadIdx.x >> 7;
      int fi = fb[chunk*128 + row];
      const float* src = maxh2 + (size_t)(b*NN + fi)*CC;
      for (int ci = chal*32; ci < chal*32+32; ++ci)
        ftile[row][ci] = s2s[ci]*src[ci] + t2s[ci];
    }
    __syncthreads();
    for (int m = mseg*32; m < mseg*32+32; ++m) {
      float accA = 0.f, accB = 0.f;
#pragma unroll
      for (int cq = 0; cq < 16; ++cq) {
        float4 f = *((const float4*)&ftile[m][cq*4]);
        accA = fmaf(f.x, wva[cq].x, accA);
        accA = fmaf(f.y, wva[cq].y, accA);
        accA = fmaf(f.z, wva[cq].z, accA);
        accA = fmaf(f.w, wva[cq].w, accA);
        accB = fmaf(f.x, wvb[cq].x, accB);
        accB = fmaf(f.y, wvb[cq].y, accB);
        accB = fmaf(f.z, wvb[cq].z, accB);
        accB = fmaf(f.w, wvb[cq].w, accB);
      }
      bestA = fmaxf(bestA, accA);
      bestB = fmaxf(bestB, accB);
    }
    __syncthreads();
  }
  red2[mseg][hl] = bestA;
  red2[mseg][64 + hl] = bestB;
  __syncthreads();
  if (threadIdx.x < 128) {
    int hh = hc*128 + threadIdx.x;
    float v = fmaxf(fmaxf(red2[0][threadIdx.x], red2[1][threadIdx.x]),
                    fmaxf(red2[2][threadIdx.x], red2[3][threadIdx.x])) + bnn1[hh];
    Y[(size_t)b*HH + hh] = fmaxf(v, 0.f);
  }
}

// ---------------- logits + log_softmax (bn3 fused per block) ----------------
__global__ __launch_bounds__(256) void logits_kernel(const float* __restrict__ Y,
    const float* __restrict__ g3, const float* __restrict__ be3,
    const float* __restrict__ w4, const float* __restrict__ b4, float* __restrict__ out) {
  int b = blockIdx.x;
  __shared__ float ybn[HH];
  __shared__ float s3s[HH], t3s[HH];
  __shared__ float lg[NCLS];
  __shared__ float lse;
  // bn3 recomputed per block (bit-identical ordering)
  for (int h = threadIdx.x; h < HH; h += 256) {
    float s = 0.f;
    for (int bb = 0; bb < BB; ++bb) s += Y[(size_t)bb*HH + h];
    float m = s / (float)BB;
    float v = 0.f;
    for (int bb = 0; bb < BB; ++bb) { float d = Y[(size_t)bb*HH + h] - m; v += d*d; }
    v /= (float)BB;
    float sc = g3[h] * rsqrtf(v + EPSF);
    s3s[h] = sc; t3s[h] = be3[h] - m*sc;
  }
  __syncthreads();
  for (int hh = threadIdx.x; hh < HH; hh += 256)
    ybn[hh] = Y[(size_t)b*HH + hh]*s3s[hh] + t3s[hh];
  __syncthreads();
  if (threadIdx.x < NCLS) {
    int j = threadIdx.x;
    float acc = b4[j];
    const float* wr = w4 + (size_t)j*HH;
    for (int ci = 0; ci < HH; ++ci) acc = fmaf(ybn[ci], wr[ci], acc);
    lg[j] = acc;
  }
  __syncthreads();
  if (threadIdx.x == 0) {
    float mx = -FLT_MAX;
    for (int j = 0; j < NCLS; ++j) mx = fmaxf(mx, lg[j]);
    float s = 0.f;
    for (int j = 0; j < NCLS; ++j) s += expf(lg[j] - mx);
    lse = mx + logf(s);
  }
  __syncthreads();
  if (threadIdx.x < NCLS) out[b*NCLS + threadIdx.x] = lg[threadIdx.x] - lse;
}

extern "C" void kernel_launch(void* const* d_in, const int* in_sizes, int n_in,
                              void* d_out, int out_size, void* d_ws, size_t ws_size,
                              hipStream_t stream) {
  const float* pos  = (const float*)d_in[0];
  const float* w1   = (const float*)d_in[1];
  const float* b1   = (const float*)d_in[2];
  const float* g1   = (const float*)d_in[3];
  const float* be1  = (const float*)d_in[4];
  const float* w2   = (const float*)d_in[5];
  const float* b2   = (const float*)d_in[6];
  const float* g2   = (const float*)d_in[7];
  const float* be2  = (const float*)d_in[8];
  const float* wnn1 = (const float*)d_in[9];
  const float* bnn1 = (const float*)d_in[10];
  const float* gbn2 = (const float*)d_in[11];
  const float* bebn2= (const float*)d_in[12];
  const float* wnn4 = (const float*)d_in[13];
  const float* bnn4 = (const float*)d_in[14];
  float* ws = (float*)d_ws;
  int*   idxg  = (int*)(ws + IDX_OFF);
  float* maxh2 = ws + MAXH2_OFF;
  int*   fidxg = (int*)(ws + FIDX_OFF);
  float* Y     = ws + Y_OFF;
  float* acc1  = ws + ACC_OFF;
  float* acc2  = ws + ACC_OFF + 128;
  unsigned short* w2bf = (unsigned short*)(ws + W2T_OFF);
  float* b2f   = ws + B2F_OFF;
  float* fpsd  = ws + FPSD_OFF;
  int*   fpsc  = (int*)(ws + FPSC_OFF);
  float* outp  = (float*)d_out;

  hipMemsetAsync((void*)(ws + ACC_OFF), 0, 256*sizeof(float), stream);
  knn_fps_kernel<<<BB + BB*32, 256, 0, stream>>>(pos, idxg, fidxg, fpsd, fpsc, w1, b1, acc1);
  fold1_kernel<<<1, 512, 0, stream>>>(acc1, g1, be1, w2, b2, w2bf, b2f);
  conv2_kernel<<<BB + BB*16, 256, 0, stream>>>(pos, idxg, w1, b1, w2bf, b2f, maxh2, acc2, fidxg, fpsd, fpsc);
  head_kernel<<<BB*4, 256, 0, stream>>>(maxh2, fidxg, acc2, g2, be2, wnn1, bnn1, Y);
  logits_kernel<<<BB, 256, 0, stream>>>(Y, gbn2, bebn2, wnn4, bnn4, outp);
}

// Round 14
// 332.272 us; speedup vs baseline: 1.2314x; 1.0105x over previous
//
#include <hip/hip_runtime.h>
#include <hip/hip_bf16.h>
#include <cfloat>
#include <math.h>

#define BB 64
#define NN 1024
#define KNN 20
#define MM 256
#define CC 64
#define HH 512
#define NCLS 40
#define EPSF 1e-5f
#define CNT1 (BB*NN*KNN)

// FPS phase boundaries: phase1 rounds [1,FPS_R1) under K1 (knn+stats),
// phase2 [FPS_R1,MM) under conv2.
#define FPS_R1 201

// workspace offsets (in 4-byte elements)
#define IDX_OFF    0
#define MAXH2_OFF  (IDX_OFF + BB*NN*KNN)      // int idx then floats
#define FIDX_OFF   (MAXH2_OFF + BB*NN*CC)
#define Y_OFF      (FIDX_OFF + BB*MM)
#define ACC_OFF    (Y_OFF + BB*HH)            // 256 floats zeroed: sum1[64],sumsq1[64],sum2[64],sumsq2[64]
#define W2T_OFF    (ACC_OFF + 256)            // w2' bf16 B-frags (2048 ushorts) + b2f
#define B2F_OFF    (W2T_OFF + CC*CC)
#define FPSD_OFF   (B2F_OFF + CC)             // BB*NN floats: FPS dist state
#define FPSC_OFF   (FPSD_OFF + BB*NN)         // BB ints: FPS cur state

typedef __attribute__((ext_vector_type(8)))  short short8;
typedef __attribute__((ext_vector_type(16))) float f32x16;

static __device__ __forceinline__ unsigned short f2bf(float f) {
  unsigned u = __float_as_uint(f);
  unsigned r = (u + 0x7fffu + ((u >> 16) & 1u)) >> 16;   // RNE
  return (unsigned short)r;
}

// orderable encode/decode: float total order <-> unsigned total order
static __device__ __forceinline__ unsigned fenc(float f) {
  unsigned b = __float_as_uint(f);
  return b ^ ((unsigned)((int)b >> 31) | 0x80000000u);
}
static __device__ __forceinline__ float fdec(unsigned e) {
  return __uint_as_float((e & 0x80000000u) ? (e & 0x7FFFFFFFu) : ~e);
}

// popcount(mask & ((1<<lane)-1)) via native mbcnt pair
static __device__ __forceinline__ int mbcnt64(unsigned long long m) {
  return (int)__builtin_amdgcn_mbcnt_hi((unsigned)(m >> 32),
           __builtin_amdgcn_mbcnt_lo((unsigned)m, 0));
}

// ---------------- generic kNN emission (float domain), wave-uniform ----------------
static __device__ __forceinline__ void knn_emit_f(const float* dq, unsigned phi, int cntHi,
                                                  int* op, int* nbr, int lane) {
  float tsf = fdec((phi << 16) | 0xFFFFu);
  if (cntHi == KNN) {
    int base = 0;
#pragma unroll
    for (int q = 0; q < 16; ++q) {
      bool pred = (dq[q] <= tsf);
      unsigned long long mask = __ballot((int)pred);
      if (pred) {
        int p_ = base + mbcnt64(mask);
        op[p_] = q*64 + lane;
        nbr[p_] = q*64 + lane;
      }
      base += (int)__popcll(mask);
    }
  } else {
    unsigned lo2 = phi << 16, hi2 = (phi << 16) | 0xFFFFu;
    while (lo2 < hi2) {
      unsigned mid = lo2 + ((hi2 - lo2) >> 1);
      float mf = fdec(mid);
      int cnt = 0;
#pragma unroll
      for (int q = 0; q < 16; ++q)
        cnt += (int)__popcll(__ballot(dq[q] <= mf));
      if (cnt >= KNN) hi2 = mid; else lo2 = mid + 1;
    }
    float xsf = fdec(lo2);
    int base = 0;
#pragma unroll
    for (int q = 0; q < 16; ++q) {
      bool pred = (dq[q] < xsf);
      unsigned long long mask = __ballot((int)pred);
      if (pred) {
        int p_ = base + mbcnt64(mask);
        op[p_] = q*64 + lane;
        nbr[p_] = q*64 + lane;
      }
      base += (int)__popcll(mask);
    }
    for (int q = 0; q < 16 && base < KNN; ++q) {  // ties, ascending index
      bool pred = (dq[q] == xsf);
      unsigned long long mask = __ballot((int)pred);
      if (pred) {
        int p_ = base + mbcnt64(mask);
        if (p_ < KNN) { op[p_] = q*64 + lane; nbr[p_] = q*64 + lane; }
      }
      base += (int)__popcll(mask);
    }
  }
}

// ---------------- FPS phase (single wave; caller: threadIdx.x < 64) ----------------
static __device__ __forceinline__ void fps_phase(
    const float* sx, const float* sy, const float* sz,   // LDS, NN each
    float* fpsd, int* fpsc, int* fidxg, int b, int mStart, int mEnd) {
  int lane = threadIdx.x;
  float lx[16], ly[16], lz[16], dist[16];
#pragma unroll
  for (int q = 0; q < 16; ++q) {
    int j = q*64 + lane;
    lx[q] = sx[j]; ly[q] = sy[j]; lz[q] = sz[j];
  }
  int cur;
  if (mStart <= 1) {
#pragma unroll
    for (int q = 0; q < 16; ++q) dist[q] = 1e38f;
    if (lane == 0) fidxg[b*MM] = 0;
    cur = 0;
  } else {
#pragma unroll
    for (int q = 0; q < 16; ++q) dist[q] = fpsd[b*NN + q*64 + lane];
    cur = fpsc[b];
  }
  for (int m = mStart; m < mEnd; ++m) {
    float cpx = sx[cur], cpy = sy[cur], cpz = sz[cur];   // uniform LDS broadcast
#pragma unroll
    for (int q = 0; q < 16; ++q) {
      float dx = __fsub_rn(lx[q], cpx);
      float dy = __fsub_rn(ly[q], cpy);
      float dz = __fsub_rn(lz[q], cpz);
      float dd = __fadd_rn(__fadd_rn(__fmul_rn(dx,dx), __fmul_rn(dy,dy)), __fmul_rn(dz,dz));
      dist[q] = fminf(dist[q], dd);
    }
    float t8[8];
#pragma unroll
    for (int q = 0; q < 8; ++q) t8[q] = fmaxf(dist[q], dist[q + 8]);
#pragma unroll
    for (int q = 0; q < 4; ++q) t8[q] = fmaxf(t8[q], t8[q + 4]);
    float r = fmaxf(fmaxf(t8[0], t8[1]), fmaxf(t8[2], t8[3]));
#define FPS_VMAX_STEP(C) { \
    int tt = __builtin_amdgcn_update_dpp(__float_as_int(r), __float_as_int(r), (C), 0xf, 0xf, false); \
    r = fmaxf(r, __int_as_float(tt)); }
    FPS_VMAX_STEP(0x111)   // row_shr:1
    FPS_VMAX_STEP(0x112)   // row_shr:2
    FPS_VMAX_STEP(0x114)   // row_shr:4
    FPS_VMAX_STEP(0x118)   // row_shr:8
    FPS_VMAX_STEP(0x142)   // row_bcast:15
    FPS_VMAX_STEP(0x143)   // row_bcast:31
#undef FPS_VMAX_STEP
    float wmax = __int_as_float(__builtin_amdgcn_readlane(__float_as_int(r), 63));
    unsigned ci = 0xFFFFFFFFu;
#pragma unroll
    for (int q = 15; q >= 0; --q)
      if (dist[q] == wmax) ci = (unsigned)(q*64 + lane);
#define FPS_IMIN_STEP(C) { \
    unsigned tt = (unsigned)__builtin_amdgcn_update_dpp((int)ci, (int)ci, (C), 0xf, 0xf, false); \
    ci = (tt < ci) ? tt : ci; }
    FPS_IMIN_STEP(0x111)
    FPS_IMIN_STEP(0x112)
    FPS_IMIN_STEP(0x114)
    FPS_IMIN_STEP(0x118)
    FPS_IMIN_STEP(0x142)
    FPS_IMIN_STEP(0x143)
#undef FPS_IMIN_STEP
    cur = (int)(unsigned)__builtin_amdgcn_readlane((int)ci, 63);
    if (lane == 0) fidxg[b*MM + m] = cur;
  }
  if (mEnd < MM) {   // checkpoint
#pragma unroll
    for (int q = 0; q < 16; ++q) fpsd[b*NN + q*64 + lane] = dist[q];
    if (lane == 0) fpsc[b] = cur;
  }
}

// ---------------- fused FPS(phase1) + kNN(paired) + BN1 stats ----------------
// blocks [0, BB): FPS rounds [1, FPS_R1).
// blocks [BB, BB + BB*32): kNN in float domain, TWO queries per iteration:
// one shared pj read feeds both distance sets; 4-value DPP bound chains,
// fused binary search with split count chains (4 independent SALU chains),
// interleaved fast-path emission. Per-query arithmetic identical to R12/R13
// -> bit-identical neighbor sets; stats in original query order.
__global__ __launch_bounds__(256) void knn_fps_kernel(const float* __restrict__ pos,
                                                      int* __restrict__ idxg,
                                                      int* __restrict__ fidxg,
                                                      float* __restrict__ fpsd,
                                                      int* __restrict__ fpsc,
                                                      const float* __restrict__ w1,
                                                      const float* __restrict__ b1,
                                                      float* __restrict__ acc1) {
  __shared__ float4 pj[NN];
  __shared__ int nbrs[4][2][KNN];
  __shared__ float red[4][CC];
  if (blockIdx.x >= BB) {
    // ---------------- kNN + stats branch ----------------
    int blk = blockIdx.x - BB;
    int b  = blk >> 5;   // cloud
    int nb = blk & 31;   // 32-point segment of the cloud
    const float* pb = pos + (size_t)b * NN * 3;
    for (int i = threadIdx.x; i < NN; i += 256) {
      float x = pb[i*3+0], y = pb[i*3+1], z = pb[i*3+2];
      pj[i] = make_float4(x, y, z, (x*x + y*y) + z*z);
    }
    __syncthreads();
    int lane = threadIdx.x & 63;
    int wv   = threadIdx.x >> 6;
    float w1x = w1[lane*3+0], w1y = w1[lane*3+1], w1z = w1[lane*3+2], b1c = b1[lane];
    float s = 0.f, ss = 0.f;

    for (int t = 0; t < 4; ++t) {
      int iA = nb*32 + wv*8 + 2*t;     // query pair (wave-uniform)
      int iB = iA + 1;
      float4 piA = pj[iA];
      float4 piB = pj[iB];
      float dA[16], dB[16];
#pragma unroll
      for (int q = 0; q < 16; ++q) {
        int j = q*64 + lane;
        float4 pw = pj[j];             // shared between the pair
        float a = piA.w + pw.w - 2.0f*(piA.x*pw.x + piA.y*pw.y + piA.z*pw.z);
        float bb2 = piB.w + pw.w - 2.0f*(piB.x*pw.x + piB.y*pw.y + piB.z*pw.z);
        if (j == iA) a = FLT_MAX;      // self excluded
        if (j == iB) bb2 = FLT_MAX;
        dA[q] = a; dB[q] = bb2;
      }
      // per-lane mins, interleaved DPP wave-min / wave-max-of-lane-mins
      float lminA = dA[0], lminB = dB[0];
#pragma unroll
      for (int q = 1; q < 16; ++q) {
        lminA = fminf(lminA, dA[q]);
        lminB = fminf(lminB, dB[q]);
      }
      float rminA = lminA, rmaxA = lminA, rminB = lminB, rmaxB = lminB;
#define KNN_DPP_STEP(C) { \
      int t1 = __builtin_amdgcn_update_dpp(__float_as_int(rminA), __float_as_int(rminA), (C), 0xf, 0xf, false); \
      int t2 = __builtin_amdgcn_update_dpp(__float_as_int(rmaxA), __float_as_int(rmaxA), (C), 0xf, 0xf, false); \
      int t3 = __builtin_amdgcn_update_dpp(__float_as_int(rminB), __float_as_int(rminB), (C), 0xf, 0xf, false); \
      int t4 = __builtin_amdgcn_update_dpp(__float_as_int(rmaxB), __float_as_int(rmaxB), (C), 0xf, 0xf, false); \
      rminA = fminf(rminA, __int_as_float(t1)); rmaxA = fmaxf(rmaxA, __int_as_float(t2)); \
      rminB = fminf(rminB, __int_as_float(t3)); rmaxB = fmaxf(rmaxB, __int_as_float(t4)); }
      KNN_DPP_STEP(0x111)   // row_shr:1
      KNN_DPP_STEP(0x112)   // row_shr:2
      KNN_DPP_STEP(0x114)   // row_shr:4
      KNN_DPP_STEP(0x118)   // row_shr:8
      KNN_DPP_STEP(0x142)   // row_bcast:15
      KNN_DPP_STEP(0x143)   // row_bcast:31
#undef KNN_DPP_STEP
      unsigned ploA = ((unsigned)__builtin_amdgcn_readlane((int)fenc(rminA), 63)) >> 16;
      unsigned phiA = ((unsigned)__builtin_amdgcn_readlane((int)fenc(rmaxA), 63)) >> 16;
      unsigned ploB = ((unsigned)__builtin_amdgcn_readlane((int)fenc(rminB), 63)) >> 16;
      unsigned phiB = ((unsigned)__builtin_amdgcn_readlane((int)fenc(rmaxB), 63)) >> 16;
      // fused binary search, split count chains
      int cntHiA = -1, cntHiB = -1;
      while (ploA < phiA || ploB < phiB) {   // wave-uniform
        unsigned pmA = (ploA + phiA) >> 1, pmB = (ploB + phiB) >> 1;
        float tfA = fdec((pmA << 16) | 0xFFFFu);
        float tfB = fdec((pmB << 16) | 0xFFFFu);
        int cA0 = 0, cA1 = 0, cB0 = 0, cB1 = 0;
#pragma unroll
        for (int q = 0; q < 8; ++q) {
          cA0 += (int)__popcll(__ballot(dA[q] <= tfA));
          cB0 += (int)__popcll(__ballot(dB[q] <= tfB));
          cA1 += (int)__popcll(__ballot(dA[q+8] <= tfA));
          cB1 += (int)__popcll(__ballot(dB[q+8] <= tfB));
        }
        int cA = cA0 + cA1, cB = cB0 + cB1;
        if (ploA < phiA) { if (cA >= KNN) { phiA = pmA; cntHiA = cA; } else ploA = pmA + 1; }
        if (ploB < phiB) { if (cB >= KNN) { phiB = pmB; cntHiB = cB; } else ploB = pmB + 1; }
      }
      float tsA = fdec((phiA << 16) | 0xFFFFu);
      float tsB = fdec((phiB << 16) | 0xFFFFu);
      if (cntHiA < 0 || cntHiB < 0) {        // fused recount at final phi
        int cA = 0, cB = 0;
#pragma unroll
        for (int q = 0; q < 16; ++q) {
          cA += (int)__popcll(__ballot(dA[q] <= tsA));
          cB += (int)__popcll(__ballot(dB[q] <= tsB));
        }
        if (cntHiA < 0) cntHiA = cA;
        if (cntHiB < 0) cntHiB = cB;
      }
      int* opA = idxg + (size_t)(b*NN + iA) * KNN;
      int* opB = idxg + (size_t)(b*NN + iB) * KNN;
      int* nbA = &nbrs[wv][0][0];
      int* nbB = &nbrs[wv][1][0];
      if (cntHiA == KNN && cntHiB == KNN) {
        // interleaved fast-path emission (dual independent base chains)
        int baseA = 0, baseB = 0;
#pragma unroll
        for (int q = 0; q < 16; ++q) {
          bool pA = (dA[q] <= tsA);
          unsigned long long mA = __ballot((int)pA);
          bool pB = (dB[q] <= tsB);
          unsigned long long mB = __ballot((int)pB);
          if (pA) { int p_ = baseA + mbcnt64(mA); opA[p_] = q*64 + lane; nbA[p_] = q*64 + lane; }
          if (pB) { int p_ = baseB + mbcnt64(mB); opB[p_] = q*64 + lane; nbB[p_] = q*64 + lane; }
          baseA += (int)__popcll(mA);
          baseB += (int)__popcll(mB);
        }
      } else {
        knn_emit_f(dA, phiA, cntHiA, opA, nbA, lane);
        knn_emit_f(dB, phiB, cntHiB, opB, nbB, lane);
      }
      // ---- BN1 stats epilogue, original query order (A then B) ----
#pragma unroll 4
      for (int k = 0; k < KNN; ++k) {
        int j = nbA[k];                // wave-uniform broadcast
        float4 pw = pj[j];
        float h = fmaxf(fmaf(pw.x - piA.x, w1x,
                       fmaf(pw.y - piA.y, w1y,
                       fmaf(pw.z - piA.z, w1z, b1c))), 0.f);
        s += h; ss += h*h;
      }
#pragma unroll 4
      for (int k = 0; k < KNN; ++k) {
        int j = nbB[k];
        float4 pw = pj[j];
        float h = fmaxf(fmaf(pw.x - piB.x, w1x,
                       fmaf(pw.y - piB.y, w1y,
                       fmaf(pw.z - piB.z, w1z, b1c))), 0.f);
        s += h; ss += h*h;
      }
    }
    // block reduce + atomics (channel = lane)
    red[wv][lane] = s; __syncthreads();
    if (wv == 0) atomicAdd(&acc1[lane], red[0][lane]+red[1][lane]+red[2][lane]+red[3][lane]);
    __syncthreads();
    red[wv][lane] = ss; __syncthreads();
    if (wv == 0) atomicAdd(&acc1[64+lane], red[0][lane]+red[1][lane]+red[2][lane]+red[3][lane]);
  } else {
    // ---------------- FPS phase 1 ----------------
    int b = blockIdx.x;
    float* base = (float*)pj;            // reuse 16 KB as 3 x NN floats
    float* sx = base; float* sy = base + NN; float* sz = base + 2*NN;
    const float* pb = pos + (size_t)b * NN * 3;
    for (int i = threadIdx.x; i < NN; i += 256) {
      sx[i] = pb[i*3+0]; sy[i] = pb[i*3+1]; sz[i] = pb[i*3+2];
    }
    __syncthreads();
    if (threadIdx.x >= 64) return;
    fps_phase(sx, sy, sz, fpsd, fpsc, fidxg, b, 1, FPS_R1);
  }
}

// ---------------- fold BN1 into w2 (bf16 B-fragment layout) ----------------
__global__ void fold1_kernel(const float* __restrict__ acc, const float* __restrict__ g1,
    const float* __restrict__ be1, const float* __restrict__ w2, const float* __restrict__ b2,
    unsigned short* __restrict__ w2bf, float* __restrict__ b2f) {
  __shared__ float s1[CC], t1[CC];
  int tid = threadIdx.x;  // 512 threads
  if (tid < CC) {
    float cnt = (float)CNT1;
    float m = acc[tid] / cnt;
    float v = acc[64+tid] / cnt - m*m;
    float sc = g1[tid] * rsqrtf(v + EPSF);
    s1[tid] = sc; t1[tid] = be1[tid] - m*sc;
  }
  __syncthreads();
  int frag = tid >> 6;        // 0..7  (nt = frag>>2, ks = frag&3)
  int lane = tid & 63;
  int nt = frag >> 2, ks = frag & 3;
  int cout = nt*32 + (lane & 31);
  int cin0 = ks*16 + (lane >> 5)*8;
  for (int j = 0; j < 8; ++j) {
    int cin = cin0 + j;
    w2bf[((size_t)frag*64 + lane)*8 + j] = f2bf(w2[cout*CC + cin] * s1[cin]);
  }
  if (tid < CC) {
    float accb = b2[tid];
    for (int ci = 0; ci < CC; ++ci) accb += t1[ci]*w2[tid*CC + ci];
    b2f[tid] = accb;
  }
}

// ---------------- conv2 via MFMA + FPS phase 2 (final) ----------------
__global__ __launch_bounds__(256, 4) void conv2_kernel(const float* __restrict__ pos,
    const int* __restrict__ idxg, const float* __restrict__ w1, const float* __restrict__ b1,
    const unsigned short* __restrict__ w2bf, const float* __restrict__ b2fg,
    float* __restrict__ maxh2, float* __restrict__ acc2,
    int* __restrict__ fidxg, float* __restrict__ fpsd, int* __restrict__ fpsc) {
  __shared__ float px[NN], py[NN], pz[NN];
  __shared__ float4 relw[4][KNN];
  __shared__ __align__(16) unsigned short h1s[4][2112];  // 8 groups * 264 ushorts
  __shared__ float redbuf[4][2*CC];
  if (blockIdx.x < BB) {
    // ---------------- FPS phase 2 (to completion) ----------------
    int b = blockIdx.x;
    const float* pb = pos + (size_t)b*NN*3;
    for (int i = threadIdx.x; i < NN; i += 256) {
      px[i] = pb[i*3+0]; py[i] = pb[i*3+1]; pz[i] = pb[i*3+2];
    }
    __syncthreads();
    if (threadIdx.x >= 64) return;
    fps_phase(px, py, pz, fpsd, fpsc, fidxg, b, FPS_R1, MM);
    return;
  }
  int blk = blockIdx.x - BB;
  int b = blk >> 4;
  int nb = blk & 15;
  const float* pb = pos + (size_t)b*NN*3;
  for (int i = threadIdx.x; i < NN; i += 256) {
    px[i] = pb[i*3+0]; py[i] = pb[i*3+1]; pz[i] = pb[i*3+2];
  }
  int lane = threadIdx.x & 63, w = threadIdx.x >> 6;
  int half = lane >> 5, l31 = lane & 31;
  short8 Bf[2][4];
#pragma unroll
  for (int nt = 0; nt < 2; ++nt)
#pragma unroll
    for (int ks = 0; ks < 4; ++ks)
      Bf[nt][ks] = *(const short8*)&w2bf[((size_t)(nt*4+ks)*64 + lane)*8];
  float b2o0 = b2fg[l31], b2o1 = b2fg[32 + l31];
  float w1x = w1[lane*3+0], w1y = w1[lane*3+1], w1z = w1[lane*3+2], b1c = b1[lane];
  unsigned short* hw = h1s[w];
  {
    short8 zz = {0,0,0,0,0,0,0,0};
    for (int z = lane; z < 96; z += 64) {
      int g = z / 12, r = 20 + z % 12;
      *(short8*)&hw[g*264 + r*8] = zz;
    }
  }
  float sA = 0.f, ssA = 0.f, sB = 0.f, ssB = 0.f;
  int nxt = 0;
  {
    int n0 = nb*64 + w*16;
    if (lane < KNN) nxt = idxg[(size_t)(b*NN + n0)*KNN + lane];
  }
  __syncthreads();
  for (int t = 0; t < 16; ++t) {
    int n = nb*64 + w*16 + t;
    if (lane < KNN) {
      int j = nxt;
      relw[w][lane] = make_float4(px[j]-px[n], py[j]-py[n], pz[j]-pz[n], 0.f);
      if (t < 15) nxt = idxg[(size_t)(b*NN + n + 1)*KNN + lane];  // prefetch
    }
    int gbase = (lane >> 3)*264 + (lane & 7);
#pragma unroll
    for (int k = 0; k < KNN; ++k) {
      float4 r4 = relw[w][k];   // wave-uniform broadcast read
      float h = fmaxf(fmaf(r4.x, w1x, fmaf(r4.y, w1y, fmaf(r4.z, w1z, b1c))), 0.f);
      hw[gbase + k*8] = f2bf(h);
    }
    f32x16 acc0 = {}; f32x16 acc1 = {};
#pragma unroll
    for (int ks = 0; ks < 4; ++ks) {
      short8 A = *(const short8*)&hw[(ks*2 + half)*264 + l31*8];
      acc0 = __builtin_amdgcn_mfma_f32_32x32x16_bf16(A, Bf[0][ks], acc0, 0, 0, 0);
      acc1 = __builtin_amdgcn_mfma_f32_32x32x16_bf16(A, Bf[1][ks], acc1, 0, 0, 0);
    }
    float mx0 = 0.f, mx1 = 0.f;
#pragma unroll
    for (int reg = 0; reg < 8; ++reg) {
      float v0 = fmaxf(acc0[reg] + b2o0, 0.f);
      float v1 = fmaxf(acc1[reg] + b2o1, 0.f);
      sA += v0; ssA += v0*v0; sB += v1; ssB += v1*v1;
      mx0 = fmaxf(mx0, v0); mx1 = fmaxf(mx1, v1);
    }
    if (half == 0) {
#pragma unroll
      for (int reg = 8; reg < 12; ++reg) {
        float v0 = fmaxf(acc0[reg] + b2o0, 0.f);
        float v1 = fmaxf(acc1[reg] + b2o1, 0.f);
        sA += v0; ssA += v0*v0; sB += v1; ssB += v1*v1;
        mx0 = fmaxf(mx0, v0); mx1 = fmaxf(mx1, v1);
      }
    }
    mx0 = fmaxf(mx0, __shfl_xor(mx0, 32, 64));
    mx1 = fmaxf(mx1, __shfl_xor(mx1, 32, 64));
    if (half == 0) {
      float* mp = maxh2 + (size_t)(b*NN + n)*CC;
      mp[l31] = mx0; mp[32 + l31] = mx1;
    }
  }
  sA += __shfl_xor(sA, 32, 64); ssA += __shfl_xor(ssA, 32, 64);
  sB += __shfl_xor(sB, 32, 64); ssB += __shfl_xor(ssB, 32, 64);
  if (half == 0) { redbuf[w][l31] = sA; redbuf[w][32 + l31] = sB; }
  __syncthreads();
  if (w == 0) atomicAdd(&acc2[lane], redbuf[0][lane]+redbuf[1][lane]+redbuf[2][lane]+redbuf[3][lane]);
  __syncthreads();
  if (half == 0) { redbuf[w][l31] = ssA; redbuf[w][32 + l31] = ssB; }
  __syncthreads();
  if (w == 0) atomicAdd(&acc2[64+lane], redbuf[0][lane]+redbuf[1][lane]+redbuf[2][lane]+redbuf[3][lane]);
}

// ---------------- head: Y[b,h] = relu(max_m(f@w_nn1^T)+b) ----------------
__global__ __launch_bounds__(256) void head_kernel(const float* __restrict__ maxh2,
    const int* __restrict__ fidxg, const float* __restrict__ acc2,
    const float* __restrict__ g2, const float* __restrict__ be2,
    const float* __restrict__ wnn1, const float* __restrict__ bnn1, float* __restrict__ Y) {
  int b = blockIdx.x >> 2;
  int hc = blockIdx.x & 3;
  __shared__ __align__(16) float ftile[128][CC];
  __shared__ float red2[4][128];
  __shared__ float s2s[CC], t2s[CC];
  if (threadIdx.x < CC) {
    int c = threadIdx.x;
    float cnt = (float)CNT1;
    float m = acc2[c]/cnt;
    float v = acc2[64+c]/cnt - m*m;
    float sc = g2[c]*rsqrtf(v+EPSF);
    s2s[c] = sc;
    t2s[c] = be2[c] - m*sc;
  }
  int hl = threadIdx.x & 63, mseg = threadIdx.x >> 6;   // 64 h-lanes x 4 msegs
  int hA = hc*128 + hl, hB = hA + 64;
  float4 wva[16], wvb[16];
  const float4* wrA = (const float4*)(wnn1 + (size_t)hA*CC);
  const float4* wrB = (const float4*)(wnn1 + (size_t)hB*CC);
#pragma unroll
  for (int q = 0; q < 16; ++q) { wva[q] = wrA[q]; wvb[q] = wrB[q]; }
  float bestA = -FLT_MAX, bestB = -FLT_MAX;
  const int* fb = fidxg + b*MM;
  __syncthreads();
  for (int chunk = 0; chunk < 2; ++chunk) {
    {
      int row = threadIdx.x & 127, chal = threadIdx.x >> 7;
      int fi = fb[chunk*128 + row];
      const float* src = maxh2 + (size_t)(b*NN + fi)*CC;
      for (int ci = chal*32; ci < chal*32+32; ++ci)
        ftile[row][ci] = s2s[ci]*src[ci] + t2s[ci];
    }
    __syncthreads();
    for (int m = mseg*32; m < mseg*32+32; ++m) {
      float accA = 0.f, accB = 0.f;
#pragma unroll
      for (int cq = 0; cq < 16; ++cq) {
        float4 f = *((const float4*)&ftile[m][cq*4]);
        accA = fmaf(f.x, wva[cq].x, accA);
        accA = fmaf(f.y, wva[cq].y, accA);
        accA = fmaf(f.z, wva[cq].z, accA);
        accA = fmaf(f.w, wva[cq].w, accA);
        accB = fmaf(f.x, wvb[cq].x, accB);
        accB = fmaf(f.y, wvb[cq].y, accB);
        accB = fmaf(f.z, wvb[cq].z, accB);
        accB = fmaf(f.w, wvb[cq].w, accB);
      }
      bestA = fmaxf(bestA, accA);
      bestB = fmaxf(bestB, accB);
    }
    __syncthreads();
  }
  red2[mseg][hl] = bestA;
  red2[mseg][64 + hl] = bestB;
  __syncthreads();
  if (threadIdx.x < 128) {
    int hh = hc*128 + threadIdx.x;
    float v = fmaxf(fmaxf(red2[0][threadIdx.x], red2[1][threadIdx.x]),
                    fmaxf(red2[2][threadIdx.x], red2[3][threadIdx.x])) + bnn1[hh];
    Y[(size_t)b*HH + hh] = fmaxf(v, 0.f);
  }
}

// ---------------- logits + log_softmax (bn3 fused per block) ----------------
__global__ __launch_bounds__(256) void logits_kernel(const float* __restrict__ Y,
    const float* __restrict__ g3, const float* __restrict__ be3,
    const float* __restrict__ w4, const float* __restrict__ b4, float* __restrict__ out) {
  int b = blockIdx.x;
  __shared__ float ybn[HH];
  __shared__ float s3s[HH], t3s[HH];
  __shared__ float lg[NCLS];
  __shared__ float lse;
  // bn3 recomputed per block (bit-identical ordering)
  for (int h = threadIdx.x; h < HH; h += 256) {
    float s = 0.f;
    for (int bb = 0; bb < BB; ++bb) s += Y[(size_t)bb*HH + h];
    float m = s / (float)BB;
    float v = 0.f;
    for (int bb = 0; bb < BB; ++bb) { float d = Y[(size_t)bb*HH + h] - m; v += d*d; }
    v /= (float)BB;
    float sc = g3[h] * rsqrtf(v + EPSF);
    s3s[h] = sc; t3s[h] = be3[h] - m*sc;
  }
  __syncthreads();
  for (int hh = threadIdx.x; hh < HH; hh += 256)
    ybn[hh] = Y[(size_t)b*HH + hh]*s3s[hh] + t3s[hh];
  __syncthreads();
  if (threadIdx.x < NCLS) {
    int j = threadIdx.x;
    float acc = b4[j];
    const float* wr = w4 + (size_t)j*HH;
    for (int ci = 0; ci < HH; ++ci) acc = fmaf(ybn[ci], wr[ci], acc);
    lg[j] = acc;
  }
  __syncthreads();
  if (threadIdx.x == 0) {
    float mx = -FLT_MAX;
    for (int j = 0; j < NCLS; ++j) mx = fmaxf(mx, lg[j]);
    float s = 0.f;
    for (int j = 0; j < NCLS; ++j) s += expf(lg[j] - mx);
    lse = mx + logf(s);
  }
  __syncthreads();
  if (threadIdx.x < NCLS) out[b*NCLS + threadIdx.x] = lg[threadIdx.x] - lse;
}

extern "C" void kernel_launch(void* const* d_in, const int* in_sizes, int n_in,
                              void* d_out, int out_size, void* d_ws, size_t ws_size,
                              hipStream_t stream) {
  const float* pos  = (const float*)d_in[0];
  const float* w1   = (const float*)d_in[1];
  const float* b1   = (const float*)d_in[2];
  const float* g1   = (const float*)d_in[3];
  const float* be1  = (const float*)d_in[4];
  const float* w2   = (const float*)d_in[5];
  const float* b2   = (const float*)d_in[6];
  const float* g2   = (const float*)d_in[7];
  const float* be2  = (const float*)d_in[8];
  const float* wnn1 = (const float*)d_in[9];
  const float* bnn1 = (const float*)d_in[10];
  const float* gbn2 = (const float*)d_in[11];
  const float* bebn2= (const float*)d_in[12];
  const float* wnn4 = (const float*)d_in[13];
  const float* bnn4 = (const float*)d_in[14];
  float* ws = (float*)d_ws;
  int*   idxg  = (int*)(ws + IDX_OFF);
  float* maxh2 = ws + MAXH2_OFF;
  int*   fidxg = (int*)(ws + FIDX_OFF);
  float* Y     = ws + Y_OFF;
  float* acc1  = ws + ACC_OFF;
  float* acc2  = ws + ACC_OFF + 128;
  unsigned short* w2bf = (unsigned short*)(ws + W2T_OFF);
  float* b2f   = ws + B2F_OFF;
  float* fpsd  = ws + FPSD_OFF;
  int*   fpsc  = (int*)(ws + FPSC_OFF);
  float* outp  = (float*)d_out;

  hipMemsetAsync((void*)(ws + ACC_OFF), 0, 256*sizeof(float), stream);
  knn_fps_kernel<<<BB + BB*32, 256, 0, stream>>>(pos, idxg, fidxg, fpsd, fpsc, w1, b1, acc1);
  fold1_kernel<<<1, 512, 0, stream>>>(acc1, g1, be1, w2, b2, w2bf, b2f);
  conv2_kernel<<<BB + BB*16, 256, 0, stream>>>(pos, idxg, w1, b1, w2bf, b2f, maxh2, acc2, fidxg, fpsd, fpsc);
  head_kernel<<<BB*4, 256, 0, stream>>>(maxh2, fidxg, acc2, g2, be2, wnn1, bnn1, Y);
  logits_kernel<<<BB, 256, 0, stream>>>(Y, gbn2, bebn2, wnn4, bnn4, outp);
}